// Round 2
// baseline (4374.128 us; speedup 1.0000x reference)
//
#include <hip/hip_runtime.h>

#define NN 100000
#define EE 1600000
// IN_C = 128, HID_C = 128, OUT_C = 64

// ---------- degree / normalization ----------
__global__ void k_deg_init(float* __restrict__ deg) {
    int i = blockIdx.x * blockDim.x + threadIdx.x;
    if (i < NN) deg[i] = 1.0f;   // self-loop weight
}

__global__ void k_deg_edges(const int* __restrict__ dst,
                            const float* __restrict__ ew,
                            float* __restrict__ deg) {
    int e = blockIdx.x * blockDim.x + threadIdx.x;
    if (e < EE) atomicAdd(&deg[dst[e]], ew[e]);
}

__global__ void k_dis(float* __restrict__ deg) {
    int i = blockIdx.x * blockDim.x + threadIdx.x;
    if (i < NN) {
        float d = deg[i];
        deg[i] = d > 0.0f ? rsqrtf(d) : 0.0f;   // deg >= 1 always (self loop)
    }
}

// ---------- GEMM1: h1[N,128] = x[N,128] @ W1[128,128] ----------
__global__ __launch_bounds__(256) void k_gemm1(const float* __restrict__ x,
                                               const float* __restrict__ W,
                                               float* __restrict__ h) {
    __shared__ float Wl[128 * 128];   // 64 KB
    __shared__ float xt[128 * 32];    // 16 KB, transposed [k][r]
    int t = threadIdx.x;
    int rb = blockIdx.x * 32;

    const float4* W4 = (const float4*)W;
    float4* Wl4 = (float4*)Wl;
#pragma unroll
    for (int i = 0; i < 16; i++) Wl4[t + 256 * i] = W4[t + 256 * i];

#pragma unroll
    for (int i = 0; i < 4; i++) {
        int idx = t + 256 * i;         // 0..1023
        int r = idx >> 5;              // 0..31
        int c4 = idx & 31;
        float4 v = ((const float4*)(x + (size_t)(rb + r) * 128))[c4];
        int kc = c4 << 2;
        xt[(kc + 0) * 32 + r] = v.x;
        xt[(kc + 1) * 32 + r] = v.y;
        xt[(kc + 2) * 32 + r] = v.z;
        xt[(kc + 3) * 32 + r] = v.w;
    }
    __syncthreads();

    int tc = t & 31;   // 32 col-groups * 4 = 128 cols
    int tr = t >> 5;   // 8 row-groups * 4 = 32 rows
    float acc[4][4] = {};
#pragma unroll 4
    for (int k = 0; k < 128; k++) {
        float4 wv = ((const float4*)(Wl + k * 128))[tc];
        float4 xv = ((const float4*)(xt + k * 32))[tr];
        float xs[4] = {xv.x, xv.y, xv.z, xv.w};
        float ws[4] = {wv.x, wv.y, wv.z, wv.w};
#pragma unroll
        for (int r = 0; r < 4; r++)
#pragma unroll
            for (int c = 0; c < 4; c++) acc[r][c] += xs[r] * ws[c];
    }
#pragma unroll
    for (int r = 0; r < 4; r++) {
        int row = rb + tr * 4 + r;
        float4 o = {acc[r][0], acc[r][1], acc[r][2], acc[r][3]};
        ((float4*)(h + (size_t)row * 128))[tc] = o;
    }
}

// ---------- GEMM2: h2[N,64] = a1[N,128] @ W2[128,64] ----------
__global__ __launch_bounds__(256) void k_gemm2(const float* __restrict__ a,
                                               const float* __restrict__ W,
                                               float* __restrict__ h) {
    __shared__ float Wl[128 * 64];    // 32 KB
    __shared__ float at[128 * 64];    // 32 KB transposed [k][r]
    int t = threadIdx.x;
    int rb = blockIdx.x * 64;

    const float4* W4 = (const float4*)W;
    float4* Wl4 = (float4*)Wl;
#pragma unroll
    for (int i = 0; i < 8; i++) Wl4[t + 256 * i] = W4[t + 256 * i];

#pragma unroll
    for (int i = 0; i < 8; i++) {
        int idx = t + 256 * i;          // 0..2047
        int r = idx >> 5;               // 0..63
        int c4 = idx & 31;
        int row = rb + r;
        if (row >= NN) row = NN - 1;    // clamp (garbage rows never stored)
        float4 v = ((const float4*)(a + (size_t)row * 128))[c4];
        int kc = c4 << 2;
        at[(kc + 0) * 64 + r] = v.x;
        at[(kc + 1) * 64 + r] = v.y;
        at[(kc + 2) * 64 + r] = v.z;
        at[(kc + 3) * 64 + r] = v.w;
    }
    __syncthreads();

    int tc = t & 15;   // 16 col-groups * 4 = 64 cols
    int tr = t >> 4;   // 16 row-groups * 4 = 64 rows
    float acc[4][4] = {};
#pragma unroll 4
    for (int k = 0; k < 128; k++) {
        float4 wv = ((const float4*)(Wl + k * 64))[tc];
        float4 av = ((const float4*)(at + k * 64))[tr];
        float as[4] = {av.x, av.y, av.z, av.w};
        float ws[4] = {wv.x, wv.y, wv.z, wv.w};
#pragma unroll
        for (int r = 0; r < 4; r++)
#pragma unroll
            for (int c = 0; c < 4; c++) acc[r][c] += as[r] * ws[c];
    }
#pragma unroll
    for (int r = 0; r < 4; r++) {
        int row = rb + tr * 4 + r;
        if (row < NN) {
            float4 o = {acc[r][0], acc[r][1], acc[r][2], acc[r][3]};
            ((float4*)(h + (size_t)row * 64))[tc] = o;
        }
    }
}

// ---------- layer-1 aggregation ----------
// self-loop init: a1 = dis^2 * h1
__global__ void k_self1(const float* __restrict__ h, const float* __restrict__ dis,
                        float* __restrict__ a) {
    int i = blockIdx.x * blockDim.x + threadIdx.x;   // N*32 float4 slots
    if (i >= NN * 32) return;
    int node = i >> 5;
    float s = dis[node];
    s = s * s;
    float4 v = ((const float4*)h)[i];
    float4 o = {v.x * s, v.y * s, v.z * s, v.w * s};
    ((float4*)a)[i] = o;
}

// edge scatter: a1[dst] += dis[src]*ew*dis[dst] * h1[src]   (32 lanes/edge, f4)
__global__ __launch_bounds__(256) void k_edge1(const int* __restrict__ src,
                                               const int* __restrict__ dst,
                                               const float* __restrict__ ew,
                                               const float* __restrict__ dis,
                                               const float* __restrict__ h,
                                               float* __restrict__ a) {
    int g = blockIdx.x * blockDim.x + threadIdx.x;
    int e = g >> 5;
    int lane = g & 31;
    if (e >= EE) return;
    int s = src[e];
    int d = dst[e];
    float coef = dis[s] * ew[e] * dis[d];
    float4 v = ((const float4*)h)[s * 32 + lane];
    float* ap = a + (size_t)d * 128 + lane * 4;
    atomicAdd(ap + 0, coef * v.x);
    atomicAdd(ap + 1, coef * v.y);
    atomicAdd(ap + 2, coef * v.z);
    atomicAdd(ap + 3, coef * v.w);
}

// bias + relu in place on a1
__global__ void k_relubias(float* __restrict__ a, const float* __restrict__ b) {
    int i = blockIdx.x * blockDim.x + threadIdx.x;   // N*32 float4 slots
    if (i >= NN * 32) return;
    int c4 = i & 31;
    float4 bv = ((const float4*)b)[c4];
    float4 v = ((float4*)a)[i];
    v.x = fmaxf(v.x + bv.x, 0.0f);
    v.y = fmaxf(v.y + bv.y, 0.0f);
    v.z = fmaxf(v.z + bv.z, 0.0f);
    v.w = fmaxf(v.w + bv.w, 0.0f);
    ((float4*)a)[i] = v;
}

// ---------- layer-2 aggregation ----------
// out = dis^2 * h2 + b2
__global__ void k_self2(const float* __restrict__ h2, const float* __restrict__ dis,
                        const float* __restrict__ b2, float* __restrict__ out) {
    int i = blockIdx.x * blockDim.x + threadIdx.x;   // N*16 float4 slots
    if (i >= NN * 16) return;
    int node = i >> 4;
    int c4 = i & 15;
    float s = dis[node];
    s = s * s;
    float4 v = ((const float4*)h2)[i];
    float4 bv = ((const float4*)b2)[c4];
    float4 o = {v.x * s + bv.x, v.y * s + bv.y, v.z * s + bv.z, v.w * s + bv.w};
    ((float4*)out)[i] = o;
}

// edge scatter: out[dst] += coef * h2[src]   (16 lanes/edge, f4)
__global__ __launch_bounds__(256) void k_edge2(const int* __restrict__ src,
                                               const int* __restrict__ dst,
                                               const float* __restrict__ ew,
                                               const float* __restrict__ dis,
                                               const float* __restrict__ h2,
                                               float* __restrict__ out) {
    int g = blockIdx.x * blockDim.x + threadIdx.x;
    int e = g >> 4;
    int lane = g & 15;
    if (e >= EE) return;
    int s = src[e];
    int d = dst[e];
    float coef = dis[s] * ew[e] * dis[d];
    float4 v = ((const float4*)h2)[s * 16 + lane];
    float* op = out + (size_t)d * 64 + lane * 4;
    atomicAdd(op + 0, coef * v.x);
    atomicAdd(op + 1, coef * v.y);
    atomicAdd(op + 2, coef * v.z);
    atomicAdd(op + 3, coef * v.w);
}

extern "C" void kernel_launch(void* const* d_in, const int* in_sizes, int n_in,
                              void* d_out, int out_size, void* d_ws, size_t ws_size,
                              hipStream_t stream) {
    const float* x  = (const float*)d_in[0];
    const int* ei   = (const int*)d_in[1];    // int inputs delivered as int32
    const float* ew = (const float*)d_in[2];
    const float* W1 = (const float*)d_in[3];
    const float* b1 = (const float*)d_in[4];
    const float* W2 = (const float*)d_in[5];
    const float* b2 = (const float*)d_in[6];
    float* out      = (float*)d_out;

    const int* src = ei;        // edge_index[0]
    const int* dst = ei + EE;   // edge_index[1]

    // workspace layout (fp32): dis[102400] | h1[N*128] (reused as h2[N*64]) | a1[N*128]
    float* dis = (float*)d_ws;
    float* h1  = dis + 102400;
    float* a1  = h1 + (size_t)NN * 128;

    k_deg_init<<<(NN + 255) / 256, 256, 0, stream>>>(dis);
    k_deg_edges<<<EE / 256, 256, 0, stream>>>(dst, ew, dis);
    k_dis<<<(NN + 255) / 256, 256, 0, stream>>>(dis);

    // layer 1
    k_gemm1<<<NN / 32, 256, 0, stream>>>(x, W1, h1);
    k_self1<<<NN * 32 / 256, 256, 0, stream>>>(h1, dis, a1);
    k_edge1<<<(EE / 256) * 32, 256, 0, stream>>>(src, dst, ew, dis, h1, a1);
    k_relubias<<<NN * 32 / 256, 256, 0, stream>>>(a1, b1);

    // layer 2 (h2 reuses h1 buffer)
    k_gemm2<<<(NN + 63) / 64, 256, 0, stream>>>(a1, W2, h1);
    k_self2<<<NN * 16 / 256, 256, 0, stream>>>(h1, dis, b2, out);
    k_edge2<<<(EE / 256) * 16, 256, 0, stream>>>(src, dst, ew, dis, h1, out);
}

// Round 3
// 710.022 us; speedup vs baseline: 6.1605x; 6.1605x over previous
//
#include <hip/hip_runtime.h>

#define NN 100000
#define EE 1600000
#define NB 391   // ceil(NN/256)
// IN_C = 128, HID_C = 128, OUT_C = 64

// ---------- init: deg=1 (self loop), hist=0 ----------
__global__ void k_init(float* __restrict__ deg, int* __restrict__ hist) {
    int i = blockIdx.x * blockDim.x + threadIdx.x;
    if (i < NN) { deg[i] = 1.0f; hist[i] = 0; }
}

// ---------- per-edge: degree sum + in-degree histogram ----------
__global__ void k_deg_hist(const int* __restrict__ dst, const float* __restrict__ ew,
                           float* __restrict__ deg, int* __restrict__ hist) {
    int e = blockIdx.x * blockDim.x + threadIdx.x;
    if (e >= EE) return;
    int d = dst[e];
    atomicAdd(&deg[d], ew[e]);
    atomicAdd(&hist[d], 1);
}

__global__ void k_dis(float* __restrict__ deg) {
    int i = blockIdx.x * blockDim.x + threadIdx.x;
    if (i < NN) {
        float d = deg[i];
        deg[i] = d > 0.0f ? rsqrtf(d) : 0.0f;   // deg >= 1 (self loop)
    }
}

// ---------- exclusive scan of hist -> rowptr (2-level) ----------
__global__ __launch_bounds__(256) void k_scan_blk(const int* __restrict__ hist,
                                                  int* __restrict__ rowptr,
                                                  int* __restrict__ bsum) {
    __shared__ int buf[2][256];
    int t = threadIdx.x;
    int i = blockIdx.x * 256 + t;
    int v = (i < NN) ? hist[i] : 0;
    int pi = 0;
    buf[0][t] = v;
    __syncthreads();
    for (int off = 1; off < 256; off <<= 1) {
        int po = pi ^ 1;
        int add = (t >= off) ? buf[pi][t - off] : 0;
        buf[po][t] = buf[pi][t] + add;
        __syncthreads();
        pi = po;
    }
    int incl = buf[pi][t];
    if (i < NN) rowptr[i] = incl - v;            // exclusive within block
    if (t == 255) bsum[blockIdx.x] = incl;       // block total
}

__global__ __launch_bounds__(512) void k_scan_top(int* __restrict__ bsum) {
    __shared__ int buf[2][512];
    int t = threadIdx.x;
    int v = (t < NB) ? bsum[t] : 0;
    int pi = 0;
    buf[0][t] = v;
    __syncthreads();
    for (int off = 1; off < 512; off <<= 1) {
        int po = pi ^ 1;
        int add = (t >= off) ? buf[pi][t - off] : 0;
        buf[po][t] = buf[pi][t] + add;
        __syncthreads();
        pi = po;
    }
    int incl = buf[pi][t];
    if (t < NB) bsum[t] = incl - v;              // exclusive block offsets
}

__global__ void k_scan_add(int* __restrict__ rowptr, const int* __restrict__ bsum,
                           int* __restrict__ cursor) {
    int i = blockIdx.x * 256 + threadIdx.x;
    if (i < NN) {
        int r = rowptr[i] + bsum[i >> 8];
        rowptr[i] = r;
        cursor[i] = r;
    }
    if (i == 0) rowptr[NN] = EE;
}

// ---------- counting-sort scatter: es/wl sorted by dst ----------
__global__ void k_scatter(const int* __restrict__ src, const int* __restrict__ dst,
                          const float* __restrict__ ew, const float* __restrict__ dis,
                          int* __restrict__ cursor, int* __restrict__ es,
                          float* __restrict__ wl) {
    int e = blockIdx.x * blockDim.x + threadIdx.x;
    if (e >= EE) return;
    int d = dst[e];
    int s = src[e];
    int pos = atomicAdd(&cursor[d], 1);
    es[pos] = s;
    wl[pos] = dis[s] * ew[e];                    // dis[dst] factored out
}

// ---------- GEMM1: h1[N,128] = x[N,128] @ W1[128,128] ----------
__global__ __launch_bounds__(256) void k_gemm1(const float* __restrict__ x,
                                               const float* __restrict__ W,
                                               float* __restrict__ h) {
    __shared__ float Wl[128 * 128];   // 64 KB
    __shared__ float xt[128 * 32];    // 16 KB, transposed [k][r]
    int t = threadIdx.x;
    int rb = blockIdx.x * 32;

    const float4* W4 = (const float4*)W;
    float4* Wl4 = (float4*)Wl;
#pragma unroll
    for (int i = 0; i < 16; i++) Wl4[t + 256 * i] = W4[t + 256 * i];

#pragma unroll
    for (int i = 0; i < 4; i++) {
        int idx = t + 256 * i;         // 0..1023
        int r = idx >> 5;              // 0..31
        int c4 = idx & 31;
        float4 v = ((const float4*)(x + (size_t)(rb + r) * 128))[c4];
        int kc = c4 << 2;
        xt[(kc + 0) * 32 + r] = v.x;
        xt[(kc + 1) * 32 + r] = v.y;
        xt[(kc + 2) * 32 + r] = v.z;
        xt[(kc + 3) * 32 + r] = v.w;
    }
    __syncthreads();

    int tc = t & 31;
    int tr = t >> 5;
    float acc[4][4] = {};
#pragma unroll 4
    for (int k = 0; k < 128; k++) {
        float4 wv = ((const float4*)(Wl + k * 128))[tc];
        float4 xv = ((const float4*)(xt + k * 32))[tr];
        float xs[4] = {xv.x, xv.y, xv.z, xv.w};
        float ws[4] = {wv.x, wv.y, wv.z, wv.w};
#pragma unroll
        for (int r = 0; r < 4; r++)
#pragma unroll
            for (int c = 0; c < 4; c++) acc[r][c] += xs[r] * ws[c];
    }
#pragma unroll
    for (int r = 0; r < 4; r++) {
        int row = rb + tr * 4 + r;
        float4 o = {acc[r][0], acc[r][1], acc[r][2], acc[r][3]};
        ((float4*)(h + (size_t)row * 128))[tc] = o;
    }
}

// ---------- GEMM2: h2[N,64] = a1[N,128] @ W2[128,64] ----------
__global__ __launch_bounds__(256) void k_gemm2(const float* __restrict__ a,
                                               const float* __restrict__ W,
                                               float* __restrict__ h) {
    __shared__ float Wl[128 * 64];
    __shared__ float at[128 * 64];
    int t = threadIdx.x;
    int rb = blockIdx.x * 64;

    const float4* W4 = (const float4*)W;
    float4* Wl4 = (float4*)Wl;
#pragma unroll
    for (int i = 0; i < 8; i++) Wl4[t + 256 * i] = W4[t + 256 * i];

#pragma unroll
    for (int i = 0; i < 8; i++) {
        int idx = t + 256 * i;
        int r = idx >> 5;
        int c4 = idx & 31;
        int row = rb + r;
        if (row >= NN) row = NN - 1;
        float4 v = ((const float4*)(a + (size_t)row * 128))[c4];
        int kc = c4 << 2;
        at[(kc + 0) * 64 + r] = v.x;
        at[(kc + 1) * 64 + r] = v.y;
        at[(kc + 2) * 64 + r] = v.z;
        at[(kc + 3) * 64 + r] = v.w;
    }
    __syncthreads();

    int tc = t & 15;
    int tr = t >> 4;
    float acc[4][4] = {};
#pragma unroll 4
    for (int k = 0; k < 128; k++) {
        float4 wv = ((const float4*)(Wl + k * 64))[tc];
        float4 av = ((const float4*)(at + k * 64))[tr];
        float as[4] = {av.x, av.y, av.z, av.w};
        float ws[4] = {wv.x, wv.y, wv.z, wv.w};
#pragma unroll
        for (int r = 0; r < 4; r++)
#pragma unroll
            for (int c = 0; c < 4; c++) acc[r][c] += as[r] * ws[c];
    }
#pragma unroll
    for (int r = 0; r < 4; r++) {
        int row = rb + tr * 4 + r;
        if (row < NN) {
            float4 o = {acc[r][0], acc[r][1], acc[r][2], acc[r][3]};
            ((float4*)(h + (size_t)row * 64))[tc] = o;
        }
    }
}

// ---------- layer-1 CSR aggregation: one wave per dst node ----------
// a1[d] = relu( dis[d] * sum_e wl[e]*h1[es[e]]  + dis[d]^2 * h1[d] + b1 )
__global__ __launch_bounds__(256) void k_agg1(const int* __restrict__ rowptr,
                                              const int* __restrict__ es,
                                              const float* __restrict__ wl,
                                              const float* __restrict__ dis,
                                              const float* __restrict__ h,
                                              const float* __restrict__ b,
                                              float* __restrict__ a) {
    int wid = (blockIdx.x * blockDim.x + threadIdx.x) >> 6;   // node id
    int lane = threadIdx.x & 63;
    if (wid >= NN) return;
    int beg = rowptr[wid], end = rowptr[wid + 1];
    const float2* h2p = (const float2*)h;
    float2 acc0 = {0.f, 0.f}, acc1 = {0.f, 0.f};
    int j = beg;
    for (; j + 1 < end; j += 2) {
        int s0 = es[j];     float w0 = wl[j];
        int s1 = es[j + 1]; float w1 = wl[j + 1];
        float2 v0 = h2p[(size_t)s0 * 64 + lane];
        float2 v1 = h2p[(size_t)s1 * 64 + lane];
        acc0.x += w0 * v0.x; acc0.y += w0 * v0.y;
        acc1.x += w1 * v1.x; acc1.y += w1 * v1.y;
    }
    if (j < end) {
        int s0 = es[j]; float w0 = wl[j];
        float2 v0 = h2p[(size_t)s0 * 64 + lane];
        acc0.x += w0 * v0.x; acc0.y += w0 * v0.y;
    }
    float di = dis[wid];
    float2 hv = h2p[(size_t)wid * 64 + lane];
    float2 bv = ((const float2*)b)[lane];
    float ox = di * (acc0.x + acc1.x) + di * di * hv.x + bv.x;
    float oy = di * (acc0.y + acc1.y) + di * di * hv.y + bv.y;
    float2 o = {fmaxf(ox, 0.f), fmaxf(oy, 0.f)};
    ((float2*)a)[(size_t)wid * 64 + lane] = o;
}

// ---------- layer-2 CSR aggregation: one wave per dst node ----------
// out[d] = dis[d] * sum_e wl[e]*h2[es[e]] + dis[d]^2 * h2[d] + b2
__global__ __launch_bounds__(256) void k_agg2(const int* __restrict__ rowptr,
                                              const int* __restrict__ es,
                                              const float* __restrict__ wl,
                                              const float* __restrict__ dis,
                                              const float* __restrict__ h,
                                              const float* __restrict__ b,
                                              float* __restrict__ out) {
    int wid = (blockIdx.x * blockDim.x + threadIdx.x) >> 6;
    int lane = threadIdx.x & 63;
    if (wid >= NN) return;
    int beg = rowptr[wid], end = rowptr[wid + 1];
    float acc0 = 0.f, acc1 = 0.f;
    int j = beg;
    for (; j + 1 < end; j += 2) {
        int s0 = es[j];     float w0 = wl[j];
        int s1 = es[j + 1]; float w1 = wl[j + 1];
        acc0 += w0 * h[(size_t)s0 * 64 + lane];
        acc1 += w1 * h[(size_t)s1 * 64 + lane];
    }
    if (j < end) acc0 += wl[j] * h[(size_t)es[j] * 64 + lane];
    float di = dis[wid];
    out[(size_t)wid * 64 + lane] =
        di * (acc0 + acc1) + di * di * h[(size_t)wid * 64 + lane] + b[lane];
}

extern "C" void kernel_launch(void* const* d_in, const int* in_sizes, int n_in,
                              void* d_out, int out_size, void* d_ws, size_t ws_size,
                              hipStream_t stream) {
    const float* x  = (const float*)d_in[0];
    const int* ei   = (const int*)d_in[1];
    const float* ew = (const float*)d_in[2];
    const float* W1 = (const float*)d_in[3];
    const float* b1 = (const float*)d_in[4];
    const float* W2 = (const float*)d_in[5];
    const float* b2 = (const float*)d_in[6];
    float* out      = (float*)d_out;

    const int* src = ei;        // edge_index[0]
    const int* dst = ei + EE;   // edge_index[1]

    // workspace layout (4B words):
    float* dis  = (float*)d_ws;            // 102400
    int* hist   = (int*)(dis + 102400);    // 102400
    int* rowptr = hist + 102400;           // 102528 (NN+1 used)
    int* cursor = rowptr + 102528;         // 102400
    int* bsum   = cursor + 102400;         // 512
    int* es     = bsum + 512;              // EE
    float* wl   = (float*)(es + EE);       // EE
    float* h1   = wl + EE;                 // NN*128 (reused as h2: NN*64)
    float* a1   = h1 + (size_t)NN * 128;   // NN*128

    // --- graph preprocessing (shared by both layers) ---
    k_init<<<NB, 256, 0, stream>>>(dis, hist);
    k_deg_hist<<<EE / 256, 256, 0, stream>>>(dst, ew, dis, hist);
    k_dis<<<NB, 256, 0, stream>>>(dis);
    k_scan_blk<<<NB, 256, 0, stream>>>(hist, rowptr, bsum);
    k_scan_top<<<1, 512, 0, stream>>>(bsum);
    k_scan_add<<<NB, 256, 0, stream>>>(rowptr, bsum, cursor);
    k_scatter<<<EE / 256, 256, 0, stream>>>(src, dst, ew, dis, cursor, es, wl);

    // --- layer 1 ---
    k_gemm1<<<NN / 32, 256, 0, stream>>>(x, W1, h1);
    k_agg1<<<(NN * 64 + 255) / 256, 256, 0, stream>>>(rowptr, es, wl, dis, h1, b1, a1);

    // --- layer 2 (h2 reuses h1 buffer) ---
    k_gemm2<<<(NN + 63) / 64, 256, 0, stream>>>(a1, W2, h1);
    k_agg2<<<(NN * 64 + 255) / 256, 256, 0, stream>>>(rowptr, es, wl, dis, h1, b2, out);
}

// Round 4
// 669.239 us; speedup vs baseline: 6.5360x; 1.0609x over previous
//
#include <hip/hip_runtime.h>

#define NN 100000
#define EE 1600000
#define NB 391   // ceil(NN/256)
// IN_C = 128, HID_C = 128, OUT_C = 64

typedef unsigned int uint;
typedef unsigned short ushort;

__device__ inline ushort f2bf(float f) {          // RNE float->bf16
    uint u = __float_as_uint(f);
    return (ushort)((u + 0x7fffu + ((u >> 16) & 1u)) >> 16);
}
__device__ inline float bf_lo(uint u) { return __uint_as_float(u << 16); }
__device__ inline float bf_hi(uint u) { return __uint_as_float(u & 0xffff0000u); }

// ---------- init: deg=1 (self loop), hist=0 ----------
__global__ void k_init(float* __restrict__ deg, int* __restrict__ hist) {
    int i = blockIdx.x * blockDim.x + threadIdx.x;
    if (i < NN) { deg[i] = 1.0f; hist[i] = 0; }
}

// ---------- per-edge: degree sum + in-degree histogram ----------
__global__ void k_deg_hist(const int* __restrict__ dst, const float* __restrict__ ew,
                           float* __restrict__ deg, int* __restrict__ hist) {
    int e = blockIdx.x * blockDim.x + threadIdx.x;
    if (e >= EE) return;
    int d = dst[e];
    atomicAdd(&deg[d], ew[e]);
    atomicAdd(&hist[d], 1);
}

__global__ void k_dis(float* __restrict__ deg) {
    int i = blockIdx.x * blockDim.x + threadIdx.x;
    if (i < NN) {
        float d = deg[i];
        deg[i] = d > 0.0f ? rsqrtf(d) : 0.0f;   // deg >= 1 (self loop)
    }
}

// ---------- exclusive scan of hist -> rowptr (2-level) ----------
__global__ __launch_bounds__(256) void k_scan_blk(const int* __restrict__ hist,
                                                  int* __restrict__ rowptr,
                                                  int* __restrict__ bsum) {
    __shared__ int buf[2][256];
    int t = threadIdx.x;
    int i = blockIdx.x * 256 + t;
    int v = (i < NN) ? hist[i] : 0;
    int pi = 0;
    buf[0][t] = v;
    __syncthreads();
    for (int off = 1; off < 256; off <<= 1) {
        int po = pi ^ 1;
        int add = (t >= off) ? buf[pi][t - off] : 0;
        buf[po][t] = buf[pi][t] + add;
        __syncthreads();
        pi = po;
    }
    int incl = buf[pi][t];
    if (i < NN) rowptr[i] = incl - v;            // exclusive within block
    if (t == 255) bsum[blockIdx.x] = incl;       // block total
}

__global__ __launch_bounds__(512) void k_scan_top(int* __restrict__ bsum) {
    __shared__ int buf[2][512];
    int t = threadIdx.x;
    int v = (t < NB) ? bsum[t] : 0;
    int pi = 0;
    buf[0][t] = v;
    __syncthreads();
    for (int off = 1; off < 512; off <<= 1) {
        int po = pi ^ 1;
        int add = (t >= off) ? buf[pi][t - off] : 0;
        buf[po][t] = buf[pi][t] + add;
        __syncthreads();
        pi = po;
    }
    int incl = buf[pi][t];
    if (t < NB) bsum[t] = incl - v;              // exclusive block offsets
}

__global__ void k_scan_add(int* __restrict__ rowptr, const int* __restrict__ bsum,
                           int* __restrict__ cursor) {
    int i = blockIdx.x * 256 + threadIdx.x;
    if (i < NN) {
        int r = rowptr[i] + bsum[i >> 8];
        rowptr[i] = r;
        cursor[i] = r;
    }
    if (i == 0) rowptr[NN] = EE;
}

// ---------- counting-sort scatter: epk[(src, w)] sorted by dst ----------
__global__ void k_scatter(const int* __restrict__ src, const int* __restrict__ dst,
                          const float* __restrict__ ew, const float* __restrict__ dis,
                          int* __restrict__ cursor, int2* __restrict__ epk) {
    int e = blockIdx.x * blockDim.x + threadIdx.x;
    if (e >= EE) return;
    int d = dst[e];
    int s = src[e];
    int pos = atomicAdd(&cursor[d], 1);
    float w = dis[s] * ew[e];                    // dis[dst] factored out
    epk[pos] = make_int2(s, __float_as_int(w));
}

// ---------- GEMM1: h1[N,128](bf16) = x[N,128] @ W1[128,128] ----------
__global__ __launch_bounds__(256) void k_gemm1(const float* __restrict__ x,
                                               const float* __restrict__ W,
                                               ushort* __restrict__ h) {
    __shared__ float Wl[128 * 128];   // 64 KB
    __shared__ float xt[128 * 32];    // 16 KB, transposed [k][r]
    int t = threadIdx.x;
    int rb = blockIdx.x * 32;

    const float4* W4 = (const float4*)W;
    float4* Wl4 = (float4*)Wl;
#pragma unroll
    for (int i = 0; i < 16; i++) Wl4[t + 256 * i] = W4[t + 256 * i];

#pragma unroll
    for (int i = 0; i < 4; i++) {
        int idx = t + 256 * i;         // 0..1023
        int r = idx >> 5;              // 0..31
        int c4 = idx & 31;
        float4 v = ((const float4*)(x + (size_t)(rb + r) * 128))[c4];
        int kc = c4 << 2;
        xt[(kc + 0) * 32 + r] = v.x;
        xt[(kc + 1) * 32 + r] = v.y;
        xt[(kc + 2) * 32 + r] = v.z;
        xt[(kc + 3) * 32 + r] = v.w;
    }
    __syncthreads();

    int tc = t & 31;
    int tr = t >> 5;
    float acc[4][4] = {};
#pragma unroll 4
    for (int k = 0; k < 128; k++) {
        float4 wv = ((const float4*)(Wl + k * 128))[tc];
        float4 xv = ((const float4*)(xt + k * 32))[tr];
        float xs[4] = {xv.x, xv.y, xv.z, xv.w};
        float ws[4] = {wv.x, wv.y, wv.z, wv.w};
#pragma unroll
        for (int r = 0; r < 4; r++)
#pragma unroll
            for (int c = 0; c < 4; c++) acc[r][c] += xs[r] * ws[c];
    }
#pragma unroll
    for (int r = 0; r < 4; r++) {
        int row = rb + tr * 4 + r;
        ushort4 o = {f2bf(acc[r][0]), f2bf(acc[r][1]), f2bf(acc[r][2]), f2bf(acc[r][3])};
        ((ushort4*)(h + (size_t)row * 128))[tc] = o;
    }
}

// ---------- GEMM2: h2[N,64](bf16) = a1[N,128] @ W2[128,64] ----------
__global__ __launch_bounds__(256) void k_gemm2(const float* __restrict__ a,
                                               const float* __restrict__ W,
                                               ushort* __restrict__ h) {
    __shared__ float Wl[128 * 64];
    __shared__ float at[128 * 64];
    int t = threadIdx.x;
    int rb = blockIdx.x * 64;

    const float4* W4 = (const float4*)W;
    float4* Wl4 = (float4*)Wl;
#pragma unroll
    for (int i = 0; i < 8; i++) Wl4[t + 256 * i] = W4[t + 256 * i];

#pragma unroll
    for (int i = 0; i < 8; i++) {
        int idx = t + 256 * i;
        int r = idx >> 5;
        int c4 = idx & 31;
        int row = rb + r;
        if (row >= NN) row = NN - 1;
        float4 v = ((const float4*)(a + (size_t)row * 128))[c4];
        int kc = c4 << 2;
        at[(kc + 0) * 64 + r] = v.x;
        at[(kc + 1) * 64 + r] = v.y;
        at[(kc + 2) * 64 + r] = v.z;
        at[(kc + 3) * 64 + r] = v.w;
    }
    __syncthreads();

    int tc = t & 15;
    int tr = t >> 4;
    float acc[4][4] = {};
#pragma unroll 4
    for (int k = 0; k < 128; k++) {
        float4 wv = ((const float4*)(Wl + k * 64))[tc];
        float4 av = ((const float4*)(at + k * 64))[tr];
        float as[4] = {av.x, av.y, av.z, av.w};
        float ws[4] = {wv.x, wv.y, wv.z, wv.w};
#pragma unroll
        for (int r = 0; r < 4; r++)
#pragma unroll
            for (int c = 0; c < 4; c++) acc[r][c] += as[r] * ws[c];
    }
#pragma unroll
    for (int r = 0; r < 4; r++) {
        int row = rb + tr * 4 + r;
        if (row < NN) {
            ushort4 o = {f2bf(acc[r][0]), f2bf(acc[r][1]), f2bf(acc[r][2]), f2bf(acc[r][3])};
            ((ushort4*)(h + (size_t)row * 64))[tc] = o;
        }
    }
}

// ---------- layer-1 CSR aggregation: one wave per dst node ----------
// a1[d] = relu( dis[d] * sum_e w[e]*h1[src[e]] + dis[d]^2 * h1[d] + b1 )
__global__ __launch_bounds__(256) void k_agg1(const int* __restrict__ rowptr,
                                              const int2* __restrict__ epk,
                                              const float* __restrict__ dis,
                                              const ushort* __restrict__ h,
                                              const float* __restrict__ b,
                                              float* __restrict__ a) {
    int wid = (blockIdx.x * blockDim.x + threadIdx.x) >> 6;   // node id
    int lane = threadIdx.x & 63;
    if (wid >= NN) return;
    int beg = rowptr[wid], end = rowptr[wid + 1];
    const uint* hp = (const uint*)h;             // 64 uints (=128 bf16) per row
    float2 acc0 = {0.f, 0.f}, acc1 = {0.f, 0.f};
    int j = beg;
    for (; j + 1 < end; j += 2) {
        int2 p0 = epk[j];
        int2 p1 = epk[j + 1];
        float w0 = __int_as_float(p0.y);
        float w1 = __int_as_float(p1.y);
        uint u0 = hp[(size_t)p0.x * 64 + lane];
        uint u1 = hp[(size_t)p1.x * 64 + lane];
        acc0.x += w0 * bf_lo(u0); acc0.y += w0 * bf_hi(u0);
        acc1.x += w1 * bf_lo(u1); acc1.y += w1 * bf_hi(u1);
    }
    if (j < end) {
        int2 p0 = epk[j];
        float w0 = __int_as_float(p0.y);
        uint u0 = hp[(size_t)p0.x * 64 + lane];
        acc0.x += w0 * bf_lo(u0); acc0.y += w0 * bf_hi(u0);
    }
    float di = dis[wid];
    uint us = hp[(size_t)wid * 64 + lane];
    float2 bv = ((const float2*)b)[lane];
    float ox = di * (acc0.x + acc1.x) + di * di * bf_lo(us) + bv.x;
    float oy = di * (acc0.y + acc1.y) + di * di * bf_hi(us) + bv.y;
    float2 o = {fmaxf(ox, 0.f), fmaxf(oy, 0.f)};
    ((float2*)a)[(size_t)wid * 64 + lane] = o;
}

// ---------- layer-2 CSR aggregation: one wave per dst node ----------
// out[d] = dis[d] * sum_e w[e]*h2[src[e]] + dis[d]^2 * h2[d] + b2
__global__ __launch_bounds__(256) void k_agg2(const int* __restrict__ rowptr,
                                              const int2* __restrict__ epk,
                                              const float* __restrict__ dis,
                                              const ushort* __restrict__ h,
                                              const float* __restrict__ b,
                                              float* __restrict__ out) {
    int wid = (blockIdx.x * blockDim.x + threadIdx.x) >> 6;
    int lane = threadIdx.x & 63;
    if (wid >= NN) return;
    int beg = rowptr[wid], end = rowptr[wid + 1];
    float acc0 = 0.f, acc1 = 0.f;
    int j = beg;
    for (; j + 1 < end; j += 2) {
        int2 p0 = epk[j];
        int2 p1 = epk[j + 1];
        float w0 = __int_as_float(p0.y);
        float w1 = __int_as_float(p1.y);
        float v0 = __uint_as_float(((uint)h[(size_t)p0.x * 64 + lane]) << 16);
        float v1 = __uint_as_float(((uint)h[(size_t)p1.x * 64 + lane]) << 16);
        acc0 += w0 * v0;
        acc1 += w1 * v1;
    }
    if (j < end) {
        int2 p0 = epk[j];
        acc0 += __int_as_float(p0.y) *
                __uint_as_float(((uint)h[(size_t)p0.x * 64 + lane]) << 16);
    }
    float di = dis[wid];
    float hv = __uint_as_float(((uint)h[(size_t)wid * 64 + lane]) << 16);
    out[(size_t)wid * 64 + lane] = di * (acc0 + acc1) + di * di * hv + b[lane];
}

extern "C" void kernel_launch(void* const* d_in, const int* in_sizes, int n_in,
                              void* d_out, int out_size, void* d_ws, size_t ws_size,
                              hipStream_t stream) {
    const float* x  = (const float*)d_in[0];
    const int* ei   = (const int*)d_in[1];
    const float* ew = (const float*)d_in[2];
    const float* W1 = (const float*)d_in[3];
    const float* b1 = (const float*)d_in[4];
    const float* W2 = (const float*)d_in[5];
    const float* b2 = (const float*)d_in[6];
    float* out      = (float*)d_out;

    const int* src = ei;        // edge_index[0]
    const int* dst = ei + EE;   // edge_index[1]

    // workspace layout (4B words):
    float* dis  = (float*)d_ws;            // 102400
    int* hist   = (int*)(dis + 102400);    // 102400
    int* rowptr = hist + 102400;           // 102528 (NN+1 used)
    int* cursor = rowptr + 102528;         // 102400
    int* bsum   = cursor + 102400;         // 512
    int2* epk   = (int2*)(bsum + 512);     // EE int2 = 2*EE words
    ushort* hb  = (ushort*)(epk + EE);     // NN*128 bf16 (reused as h2: NN*64)
    float* a1   = (float*)(hb + (size_t)NN * 128);   // NN*128 fp32

    // --- graph preprocessing (shared by both layers) ---
    k_init<<<NB, 256, 0, stream>>>(dis, hist);
    k_deg_hist<<<EE / 256, 256, 0, stream>>>(dst, ew, dis, hist);
    k_dis<<<NB, 256, 0, stream>>>(dis);
    k_scan_blk<<<NB, 256, 0, stream>>>(hist, rowptr, bsum);
    k_scan_top<<<1, 512, 0, stream>>>(bsum);
    k_scan_add<<<NB, 256, 0, stream>>>(rowptr, bsum, cursor);
    k_scatter<<<EE / 256, 256, 0, stream>>>(src, dst, ew, dis, cursor, epk);

    // --- layer 1 ---
    k_gemm1<<<NN / 32, 256, 0, stream>>>(x, W1, hb);
    k_agg1<<<(NN * 64 + 255) / 256, 256, 0, stream>>>(rowptr, epk, dis, hb, b1, a1);

    // --- layer 2 (h2 reuses hb buffer) ---
    k_gemm2<<<(NN + 63) / 64, 256, 0, stream>>>(a1, W2, hb);
    k_agg2<<<(NN * 64 + 255) / 256, 256, 0, stream>>>(rowptr, epk, dis, hb, b2, out);
}

// Round 6
// 574.245 us; speedup vs baseline: 7.6172x; 1.1654x over previous
//
#include <hip/hip_runtime.h>

#define NN 100000
#define EE 1600000
#define NB 391   // ceil(NN/256)
// IN_C = 128, HID_C = 128, OUT_C = 64

typedef unsigned int uint;
typedef unsigned short ushort;
typedef unsigned long long u64;

#define FIXMASK ((1ull << 40) - 1)

__device__ inline ushort f2bf(float f) {          // RNE float->bf16
    uint u = __float_as_uint(f);
    return (ushort)((u + 0x7fffu + ((u >> 16) & 1u)) >> 16);
}
__device__ inline float bf_lo(uint u) { return __uint_as_float(u << 16); }
__device__ inline float bf_hi(uint u) { return __uint_as_float(u & 0xffff0000u); }

// ---------- init: packed (count | fixed-point ew sum) = 0 ----------
__global__ void k_init(u64* __restrict__ dh) {
    int i = blockIdx.x * blockDim.x + threadIdx.x;
    if (i < NN) dh[i] = 0ull;
}

// ---------- per-edge: ONE packed u64 atomic (count<<40 | ew*2^24) ----------
__global__ void k_dh(const int* __restrict__ dst, const float* __restrict__ ew,
                     u64* __restrict__ dh) {
    int e = blockIdx.x * blockDim.x + threadIdx.x;
    if (e >= EE) return;
    int d = dst[e];
    u64 w = (u64)(ew[e] * 16777216.0f + 0.5f);
    atomicAdd(&dh[d], (1ull << 40) | w);
}

// ---------- scan pass 1: unpack dh -> dis + in-block exclusive scan ----------
__global__ __launch_bounds__(256) void k_scan_blk(const u64* __restrict__ dh,
                                                  float* __restrict__ dis,
                                                  int* __restrict__ rowptr,
                                                  int* __restrict__ bsum) {
    __shared__ int buf[2][256];
    int t = threadIdx.x;
    int i = blockIdx.x * 256 + t;
    int v = 0;
    if (i < NN) {
        u64 p = dh[i];
        v = (int)(p >> 40);
        float deg = 1.0f + (float)(p & FIXMASK) * (1.0f / 16777216.0f);
        dis[i] = rsqrtf(deg);                    // deg >= 1 always
    }
    int pi = 0;
    buf[0][t] = v;
    __syncthreads();
    for (int off = 1; off < 256; off <<= 1) {
        int po = pi ^ 1;
        int add = (t >= off) ? buf[pi][t - off] : 0;
        buf[po][t] = buf[pi][t] + add;
        __syncthreads();
        pi = po;
    }
    int incl = buf[pi][t];
    if (i < NN) rowptr[i] = incl - v;            // exclusive within block
    if (t == 255) bsum[blockIdx.x] = incl;       // block total
}

__global__ __launch_bounds__(512) void k_scan_top(int* __restrict__ bsum) {
    __shared__ int buf[2][512];
    int t = threadIdx.x;
    int v = (t < NB) ? bsum[t] : 0;
    int pi = 0;
    buf[0][t] = v;
    __syncthreads();
    for (int off = 1; off < 512; off <<= 1) {
        int po = pi ^ 1;
        int add = (t >= off) ? buf[pi][t - off] : 0;
        buf[po][t] = buf[pi][t] + add;
        __syncthreads();
        pi = po;
    }
    int incl = buf[pi][t];
    if (t < NB) bsum[t] = incl - v;              // exclusive block offsets
}

__global__ void k_scan_add(int* __restrict__ rowptr, const int* __restrict__ bsum,
                           int* __restrict__ cursor) {
    int i = blockIdx.x * 256 + threadIdx.x;
    if (i < NN) {
        int r = rowptr[i] + bsum[i >> 8];
        rowptr[i] = r;
        cursor[i] = r;
    }
    if (i == 0) rowptr[NN] = EE;
}

// ---------- counting-sort scatter: epk[(src, w)] sorted by dst ----------
__global__ void k_scatter(const int* __restrict__ src, const int* __restrict__ dst,
                          const float* __restrict__ ew, const float* __restrict__ dis,
                          int* __restrict__ cursor, int2* __restrict__ epk) {
    int e = blockIdx.x * blockDim.x + threadIdx.x;
    if (e >= EE) return;
    int d = dst[e];
    int s = src[e];
    int pos = atomicAdd(&cursor[d], 1);
    float w = dis[s] * ew[e];                    // dis[dst] factored out
    epk[pos] = make_int2(s, __float_as_int(w));
}

// ---------- GEMM1: h1[N,128](bf16) = x[N,128] @ W1[128,128] ----------
__global__ __launch_bounds__(256) void k_gemm1(const float* __restrict__ x,
                                               const float* __restrict__ W,
                                               ushort* __restrict__ h) {
    __shared__ float Wl[128 * 128];   // 64 KB
    __shared__ float xt[128 * 32];    // 16 KB, transposed [k][r]
    int t = threadIdx.x;
    int rb = blockIdx.x * 32;

    const float4* W4 = (const float4*)W;
    float4* Wl4 = (float4*)Wl;
#pragma unroll
    for (int i = 0; i < 16; i++) Wl4[t + 256 * i] = W4[t + 256 * i];

#pragma unroll
    for (int i = 0; i < 4; i++) {
        int idx = t + 256 * i;         // 0..1023
        int r = idx >> 5;              // 0..31
        int c4 = idx & 31;
        float4 v = ((const float4*)(x + (size_t)(rb + r) * 128))[c4];
        int kc = c4 << 2;
        xt[(kc + 0) * 32 + r] = v.x;
        xt[(kc + 1) * 32 + r] = v.y;
        xt[(kc + 2) * 32 + r] = v.z;
        xt[(kc + 3) * 32 + r] = v.w;
    }
    __syncthreads();

    int tc = t & 31;
    int tr = t >> 5;
    float acc[4][4] = {};
#pragma unroll 4
    for (int k = 0; k < 128; k++) {
        float4 wv = ((const float4*)(Wl + k * 128))[tc];
        float4 xv = ((const float4*)(xt + k * 32))[tr];
        float xs[4] = {xv.x, xv.y, xv.z, xv.w};
        float ws[4] = {wv.x, wv.y, wv.z, wv.w};
#pragma unroll
        for (int r = 0; r < 4; r++)
#pragma unroll
            for (int c = 0; c < 4; c++) acc[r][c] += xs[r] * ws[c];
    }
#pragma unroll
    for (int r = 0; r < 4; r++) {
        int row = rb + tr * 4 + r;
        ushort4 o = {f2bf(acc[r][0]), f2bf(acc[r][1]), f2bf(acc[r][2]), f2bf(acc[r][3])};
        ((ushort4*)(h + (size_t)row * 128))[tc] = o;
    }
}

// ---------- GEMM2: h2[N,64](bf16) = a1[N,128] @ W2[128,64] ----------
__global__ __launch_bounds__(256) void k_gemm2(const float* __restrict__ a,
                                               const float* __restrict__ W,
                                               ushort* __restrict__ h) {
    __shared__ float Wl[128 * 64];
    __shared__ float at[128 * 64];
    int t = threadIdx.x;
    int rb = blockIdx.x * 64;

    const float4* W4 = (const float4*)W;
    float4* Wl4 = (float4*)Wl;
#pragma unroll
    for (int i = 0; i < 8; i++) Wl4[t + 256 * i] = W4[t + 256 * i];

#pragma unroll
    for (int i = 0; i < 8; i++) {
        int idx = t + 256 * i;
        int r = idx >> 5;
        int c4 = idx & 31;
        int row = rb + r;
        if (row >= NN) row = NN - 1;
        float4 v = ((const float4*)(a + (size_t)row * 128))[c4];
        int kc = c4 << 2;
        at[(kc + 0) * 64 + r] = v.x;
        at[(kc + 1) * 64 + r] = v.y;
        at[(kc + 2) * 64 + r] = v.z;
        at[(kc + 3) * 64 + r] = v.w;
    }
    __syncthreads();

    int tc = t & 15;
    int tr = t >> 4;
    float acc[4][4] = {};
#pragma unroll 4
    for (int k = 0; k < 128; k++) {
        float4 wv = ((const float4*)(Wl + k * 64))[tc];
        float4 av = ((const float4*)(at + k * 64))[tr];
        float as[4] = {av.x, av.y, av.z, av.w};
        float ws[4] = {wv.x, wv.y, wv.z, wv.w};
#pragma unroll
        for (int r = 0; r < 4; r++)
#pragma unroll
            for (int c = 0; c < 4; c++) acc[r][c] += as[r] * ws[c];
    }
#pragma unroll
    for (int r = 0; r < 4; r++) {
        int row = rb + tr * 4 + r;
        if (row < NN) {
            ushort4 o = {f2bf(acc[r][0]), f2bf(acc[r][1]), f2bf(acc[r][2]), f2bf(acc[r][3])};
            ((ushort4*)(h + (size_t)row * 64))[tc] = o;
        }
    }
}

// ---------- layer-1 CSR aggregation: one wave per dst node ----------
// a1[d] = relu( dis[d] * sum_e w[e]*h1[src[e]] + dis[d]^2 * h1[d] + b1 )
__global__ __launch_bounds__(256) void k_agg1(const int* __restrict__ rowptr,
                                              const int2* __restrict__ epk,
                                              const float* __restrict__ dis,
                                              const ushort* __restrict__ h,
                                              const float* __restrict__ b,
                                              float* __restrict__ a) {
    int wid = (blockIdx.x * blockDim.x + threadIdx.x) >> 6;   // node id
    int lane = threadIdx.x & 63;
    if (wid >= NN) return;
    int beg = rowptr[wid], end = rowptr[wid + 1];
    const uint* hp = (const uint*)h;             // 64 uints (=128 bf16) per row
    float2 acc0 = {0.f, 0.f}, acc1 = {0.f, 0.f};
    int j = beg;
    for (; j + 1 < end; j += 2) {
        int2 p0 = epk[j];
        int2 p1 = epk[j + 1];
        float w0 = __int_as_float(p0.y);
        float w1 = __int_as_float(p1.y);
        uint u0 = hp[(size_t)p0.x * 64 + lane];
        uint u1 = hp[(size_t)p1.x * 64 + lane];
        acc0.x += w0 * bf_lo(u0); acc0.y += w0 * bf_hi(u0);
        acc1.x += w1 * bf_lo(u1); acc1.y += w1 * bf_hi(u1);
    }
    if (j < end) {
        int2 p0 = epk[j];
        float w0 = __int_as_float(p0.y);
        uint u0 = hp[(size_t)p0.x * 64 + lane];
        acc0.x += w0 * bf_lo(u0); acc0.y += w0 * bf_hi(u0);
    }
    float di = dis[wid];
    uint us = hp[(size_t)wid * 64 + lane];
    float2 bv = ((const float2*)b)[lane];
    float ox = di * (acc0.x + acc1.x) + di * di * bf_lo(us) + bv.x;
    float oy = di * (acc0.y + acc1.y) + di * di * bf_hi(us) + bv.y;
    float2 o = {fmaxf(ox, 0.f), fmaxf(oy, 0.f)};
    ((float2*)a)[(size_t)wid * 64 + lane] = o;
}

// ---------- layer-2 CSR aggregation: one wave per dst node ----------
// out[d] = dis[d] * sum_e w[e]*h2[src[e]] + dis[d]^2 * h2[d] + b2
__global__ __launch_bounds__(256) void k_agg2(const int* __restrict__ rowptr,
                                              const int2* __restrict__ epk,
                                              const float* __restrict__ dis,
                                              const ushort* __restrict__ h,
                                              const float* __restrict__ b,
                                              float* __restrict__ out) {
    int wid = (blockIdx.x * blockDim.x + threadIdx.x) >> 6;
    int lane = threadIdx.x & 63;
    if (wid >= NN) return;
    int beg = rowptr[wid], end = rowptr[wid + 1];
    float acc0 = 0.f, acc1 = 0.f;
    int j = beg;
    for (; j + 1 < end; j += 2) {
        int2 p0 = epk[j];
        int2 p1 = epk[j + 1];
        float w0 = __int_as_float(p0.y);
        float w1 = __int_as_float(p1.y);
        float v0 = __uint_as_float(((uint)h[(size_t)p0.x * 64 + lane]) << 16);
        float v1 = __uint_as_float(((uint)h[(size_t)p1.x * 64 + lane]) << 16);
        acc0 += w0 * v0;
        acc1 += w1 * v1;
    }
    if (j < end) {
        int2 p0 = epk[j];
        acc0 += __int_as_float(p0.y) *
                __uint_as_float(((uint)h[(size_t)p0.x * 64 + lane]) << 16);
    }
    float di = dis[wid];
    float hv = __uint_as_float(((uint)h[(size_t)wid * 64 + lane]) << 16);
    out[(size_t)wid * 64 + lane] = di * (acc0 + acc1) + di * di * hv + b[lane];
}

extern "C" void kernel_launch(void* const* d_in, const int* in_sizes, int n_in,
                              void* d_out, int out_size, void* d_ws, size_t ws_size,
                              hipStream_t stream) {
    const float* x  = (const float*)d_in[0];
    const int* ei   = (const int*)d_in[1];
    const float* ew = (const float*)d_in[2];
    const float* W1 = (const float*)d_in[3];
    const float* b1 = (const float*)d_in[4];
    const float* W2 = (const float*)d_in[5];
    const float* b2 = (const float*)d_in[6];
    float* out      = (float*)d_out;

    const int* src = ei;        // edge_index[0]
    const int* dst = ei + EE;   // edge_index[1]

    // workspace layout (4B words; d_ws is 256B-aligned so u64 first is safe):
    u64* dh     = (u64*)d_ws;              // NN u64 = 204800 words
    float* dis  = (float*)(dh + 102400);   // 102400
    int* rowptr = (int*)(dis + 102400);    // 102528 (NN+1 used)
    int* cursor = rowptr + 102528;         // 102400
    int* bsum   = cursor + 102400;         // 512
    int2* epk   = (int2*)(bsum + 512);     // EE int2 = 2*EE words
    ushort* hb  = (ushort*)(epk + EE);     // NN*128 bf16 (reused as h2: NN*64)
    float* a1   = (float*)(hb + (size_t)NN * 128);   // NN*128 fp32

    // --- graph preprocessing (shared by both layers) ---
    k_init<<<NB, 256, 0, stream>>>(dh);
    k_dh<<<EE / 256, 256, 0, stream>>>(dst, ew, dh);
    k_scan_blk<<<NB, 256, 0, stream>>>(dh, dis, rowptr, bsum);
    k_scan_top<<<1, 512, 0, stream>>>(bsum);
    k_scan_add<<<NB, 256, 0, stream>>>(rowptr, bsum, cursor);
    k_scatter<<<EE / 256, 256, 0, stream>>>(src, dst, ew, dis, cursor, epk);

    // --- layer 1 ---
    k_gemm1<<<NN / 32, 256, 0, stream>>>(x, W1, hb);
    k_agg1<<<(NN * 64 + 255) / 256, 256, 0, stream>>>(rowptr, epk, dis, hb, b1, a1);

    // --- layer 2 (h2 reuses hb buffer) ---
    k_gemm2<<<(NN + 63) / 64, 256, 0, stream>>>(a1, W2, hb);
    k_agg2<<<(NN * 64 + 255) / 256, 256, 0, stream>>>(rowptr, epk, dis, hb, b2, out);
}

// Round 8
// 538.155 us; speedup vs baseline: 8.1280x; 1.0671x over previous
//
#include <hip/hip_runtime.h>

#define NN 100000
#define EE 1600000
#define NB 391   // ceil(NN/256)
// IN_C = 128, HID_C = 128, OUT_C = 64

typedef unsigned int uint;
typedef unsigned short ushort;
typedef unsigned long long u64;

#define FIXMASK ((1ull << 40) - 1)

__device__ inline ushort f2bf(float f) {          // RNE float->bf16
    uint u = __float_as_uint(f);
    return (ushort)((u + 0x7fffu + ((u >> 16) & 1u)) >> 16);
}
__device__ inline float bf_lo(uint u) { return __uint_as_float(u << 16); }
__device__ inline float bf_hi(uint u) { return __uint_as_float(u & 0xffff0000u); }

// ---------- init: packed (count | fixed-point ew sum) = 0 ----------
__global__ void k_init(u64* __restrict__ dh) {
    int i = blockIdx.x * blockDim.x + threadIdx.x;
    if (i < NN) dh[i] = 0ull;
}

// ---------- per-edge: ONE packed u64 atomic (count<<40 | ew*2^24) ----------
__global__ void k_dh(const int* __restrict__ dst, const float* __restrict__ ew,
                     u64* __restrict__ dh) {
    int e = blockIdx.x * blockDim.x + threadIdx.x;
    if (e >= EE) return;
    int d = dst[e];
    u64 w = (u64)(ew[e] * 16777216.0f + 0.5f);
    atomicAdd(&dh[d], (1ull << 40) | w);
}

// ---------- scan pass 1: unpack dh -> dis + in-block exclusive scan ----------
__global__ __launch_bounds__(256) void k_scan_blk(const u64* __restrict__ dh,
                                                  float* __restrict__ dis,
                                                  int* __restrict__ rowptr,
                                                  int* __restrict__ bsum) {
    __shared__ int buf[2][256];
    int t = threadIdx.x;
    int i = blockIdx.x * 256 + t;
    int v = 0;
    if (i < NN) {
        u64 p = dh[i];
        v = (int)(p >> 40);
        float deg = 1.0f + (float)(p & FIXMASK) * (1.0f / 16777216.0f);
        dis[i] = rsqrtf(deg);                    // deg >= 1 always
    }
    int pi = 0;
    buf[0][t] = v;
    __syncthreads();
    for (int off = 1; off < 256; off <<= 1) {
        int po = pi ^ 1;
        int add = (t >= off) ? buf[pi][t - off] : 0;
        buf[po][t] = buf[pi][t] + add;
        __syncthreads();
        pi = po;
    }
    int incl = buf[pi][t];
    if (i < NN) rowptr[i] = incl - v;            // exclusive within block
    if (t == 255) bsum[blockIdx.x] = incl;       // block total
}

__global__ __launch_bounds__(512) void k_scan_top(int* __restrict__ bsum) {
    __shared__ int buf[2][512];
    int t = threadIdx.x;
    int v = (t < NB) ? bsum[t] : 0;
    int pi = 0;
    buf[0][t] = v;
    __syncthreads();
    for (int off = 1; off < 512; off <<= 1) {
        int po = pi ^ 1;
        int add = (t >= off) ? buf[pi][t - off] : 0;
        buf[po][t] = buf[pi][t] + add;
        __syncthreads();
        pi = po;
    }
    int incl = buf[pi][t];
    if (t < NB) bsum[t] = incl - v;              // exclusive block offsets
}

__global__ void k_scan_add(int* __restrict__ rowptr, const int* __restrict__ bsum,
                           int* __restrict__ cursor) {
    int i = blockIdx.x * 256 + threadIdx.x;
    if (i < NN) {
        int r = rowptr[i] + bsum[i >> 8];
        rowptr[i] = r;
        cursor[i] = r;
    }
    if (i == 0) rowptr[NN] = EE;
}

// ---------- counting-sort scatter: epk[(src, w)] sorted by dst ----------
__global__ void k_scatter(const int* __restrict__ src, const int* __restrict__ dst,
                          const float* __restrict__ ew, const float* __restrict__ dis,
                          int* __restrict__ cursor, int2* __restrict__ epk) {
    int e = blockIdx.x * blockDim.x + threadIdx.x;
    if (e >= EE) return;
    int d = dst[e];
    int s = src[e];
    int pos = atomicAdd(&cursor[d], 1);
    float w = dis[s] * ew[e];                    // dis[dst] factored out
    epk[pos] = make_int2(s, __float_as_int(w));
}

// ---------- GEMM1: h1[N,128](bf16) = x[N,128] @ W1[128,128] ----------
__global__ __launch_bounds__(256) void k_gemm1(const float* __restrict__ x,
                                               const float* __restrict__ W,
                                               ushort* __restrict__ h) {
    __shared__ float Wl[128 * 128];   // 64 KB
    __shared__ float xt[128 * 32];    // 16 KB, transposed [k][r]
    int t = threadIdx.x;
    int rb = blockIdx.x * 32;

    const float4* W4 = (const float4*)W;
    float4* Wl4 = (float4*)Wl;
#pragma unroll
    for (int i = 0; i < 16; i++) Wl4[t + 256 * i] = W4[t + 256 * i];

#pragma unroll
    for (int i = 0; i < 4; i++) {
        int idx = t + 256 * i;         // 0..1023
        int r = idx >> 5;              // 0..31
        int c4 = idx & 31;
        float4 v = ((const float4*)(x + (size_t)(rb + r) * 128))[c4];
        int kc = c4 << 2;
        xt[(kc + 0) * 32 + r] = v.x;
        xt[(kc + 1) * 32 + r] = v.y;
        xt[(kc + 2) * 32 + r] = v.z;
        xt[(kc + 3) * 32 + r] = v.w;
    }
    __syncthreads();

    int tc = t & 31;
    int tr = t >> 5;
    float acc[4][4] = {};
#pragma unroll 4
    for (int k = 0; k < 128; k++) {
        float4 wv = ((const float4*)(Wl + k * 128))[tc];
        float4 xv = ((const float4*)(xt + k * 32))[tr];
        float xs[4] = {xv.x, xv.y, xv.z, xv.w};
        float ws[4] = {wv.x, wv.y, wv.z, wv.w};
#pragma unroll
        for (int r = 0; r < 4; r++)
#pragma unroll
            for (int c = 0; c < 4; c++) acc[r][c] += xs[r] * ws[c];
    }
#pragma unroll
    for (int r = 0; r < 4; r++) {
        int row = rb + tr * 4 + r;
        ushort4 o = {f2bf(acc[r][0]), f2bf(acc[r][1]), f2bf(acc[r][2]), f2bf(acc[r][3])};
        ((ushort4*)(h + (size_t)row * 128))[tc] = o;
    }
}

// ---------- GEMM2: h2[N,64](bf16) = a1[N,128] @ W2[128,64] ----------
__global__ __launch_bounds__(256) void k_gemm2(const float* __restrict__ a,
                                               const float* __restrict__ W,
                                               ushort* __restrict__ h) {
    __shared__ float Wl[128 * 64];
    __shared__ float at[128 * 64];
    int t = threadIdx.x;
    int rb = blockIdx.x * 64;

    const float4* W4 = (const float4*)W;
    float4* Wl4 = (float4*)Wl;
#pragma unroll
    for (int i = 0; i < 8; i++) Wl4[t + 256 * i] = W4[t + 256 * i];

#pragma unroll
    for (int i = 0; i < 8; i++) {
        int idx = t + 256 * i;
        int r = idx >> 5;
        int c4 = idx & 31;
        int row = rb + r;
        if (row >= NN) row = NN - 1;
        float4 v = ((const float4*)(a + (size_t)row * 128))[c4];
        int kc = c4 << 2;
        at[(kc + 0) * 64 + r] = v.x;
        at[(kc + 1) * 64 + r] = v.y;
        at[(kc + 2) * 64 + r] = v.z;
        at[(kc + 3) * 64 + r] = v.w;
    }
    __syncthreads();

    int tc = t & 15;
    int tr = t >> 4;
    float acc[4][4] = {};
#pragma unroll 4
    for (int k = 0; k < 128; k++) {
        float4 wv = ((const float4*)(Wl + k * 64))[tc];
        float4 av = ((const float4*)(at + k * 64))[tr];
        float as[4] = {av.x, av.y, av.z, av.w};
        float ws[4] = {wv.x, wv.y, wv.z, wv.w};
#pragma unroll
        for (int r = 0; r < 4; r++)
#pragma unroll
            for (int c = 0; c < 4; c++) acc[r][c] += as[r] * ws[c];
    }
#pragma unroll
    for (int r = 0; r < 4; r++) {
        int row = rb + tr * 4 + r;
        if (row < NN) {
            ushort4 o = {f2bf(acc[r][0]), f2bf(acc[r][1]), f2bf(acc[r][2]), f2bf(acc[r][3])};
            ((ushort4*)(h + (size_t)row * 64))[tc] = o;
        }
    }
}

// ---------- layer-1 CSR aggregation: one wave per dst node, 4-way MLP ----------
// a1[d] = relu( dis[d] * sum_e w[e]*h1[src[e]] + dis[d]^2 * h1[d] + b1 )
__global__ __launch_bounds__(256) void k_agg1(const int* __restrict__ rowptr,
                                              const int2* __restrict__ epk,
                                              const float* __restrict__ dis,
                                              const ushort* __restrict__ h,
                                              const float* __restrict__ b,
                                              float* __restrict__ a) {
    int wid = (blockIdx.x * blockDim.x + threadIdx.x) >> 6;   // node id
    int lane = threadIdx.x & 63;
    if (wid >= NN) return;
    int beg = rowptr[wid], end = rowptr[wid + 1];
    const uint* hp = (const uint*)h;             // 64 uints (=128 bf16) per row
    // issue the self-row + bias loads early (independent of the loop)
    uint us = hp[(size_t)wid * 64 + lane];
    float di = dis[wid];
    float2 bv = ((const float2*)b)[lane];

    float2 acc0 = {0.f, 0.f}, acc1 = {0.f, 0.f};
    float2 acc2 = {0.f, 0.f}, acc3 = {0.f, 0.f};
    int j = beg;
    for (; j + 3 < end; j += 4) {
        int2 p0 = epk[j];
        int2 p1 = epk[j + 1];
        int2 p2 = epk[j + 2];
        int2 p3 = epk[j + 3];
        uint u0 = hp[(size_t)p0.x * 64 + lane];
        uint u1 = hp[(size_t)p1.x * 64 + lane];
        uint u2 = hp[(size_t)p2.x * 64 + lane];
        uint u3 = hp[(size_t)p3.x * 64 + lane];
        float w0 = __int_as_float(p0.y);
        float w1 = __int_as_float(p1.y);
        float w2 = __int_as_float(p2.y);
        float w3 = __int_as_float(p3.y);
        acc0.x += w0 * bf_lo(u0); acc0.y += w0 * bf_hi(u0);
        acc1.x += w1 * bf_lo(u1); acc1.y += w1 * bf_hi(u1);
        acc2.x += w2 * bf_lo(u2); acc2.y += w2 * bf_hi(u2);
        acc3.x += w3 * bf_lo(u3); acc3.y += w3 * bf_hi(u3);
    }
    for (; j < end; j++) {
        int2 p0 = epk[j];
        float w0 = __int_as_float(p0.y);
        uint u0 = hp[(size_t)p0.x * 64 + lane];
        acc0.x += w0 * bf_lo(u0); acc0.y += w0 * bf_hi(u0);
    }
    float sx = (acc0.x + acc1.x) + (acc2.x + acc3.x);
    float sy = (acc0.y + acc1.y) + (acc2.y + acc3.y);
    float ox = di * sx + di * di * bf_lo(us) + bv.x;
    float oy = di * sy + di * di * bf_hi(us) + bv.y;
    float2 o = {fmaxf(ox, 0.f), fmaxf(oy, 0.f)};
    ((float2*)a)[(size_t)wid * 64 + lane] = o;
}

// ---------- layer-2 CSR aggregation: one wave per dst node, 4-way MLP ----------
// out[d] = dis[d] * sum_e w[e]*h2[src[e]] + dis[d]^2 * h2[d] + b2
__global__ __launch_bounds__(256) void k_agg2(const int* __restrict__ rowptr,
                                              const int2* __restrict__ epk,
                                              const float* __restrict__ dis,
                                              const ushort* __restrict__ h,
                                              const float* __restrict__ b,
                                              float* __restrict__ out) {
    int wid = (blockIdx.x * blockDim.x + threadIdx.x) >> 6;
    int lane = threadIdx.x & 63;
    if (wid >= NN) return;
    int beg = rowptr[wid], end = rowptr[wid + 1];
    float hv = __uint_as_float(((uint)h[(size_t)wid * 64 + lane]) << 16);
    float di = dis[wid];
    float bl = b[lane];

    float acc0 = 0.f, acc1 = 0.f, acc2 = 0.f, acc3 = 0.f;
    int j = beg;
    for (; j + 3 < end; j += 4) {
        int2 p0 = epk[j];
        int2 p1 = epk[j + 1];
        int2 p2 = epk[j + 2];
        int2 p3 = epk[j + 3];
        float v0 = __uint_as_float(((uint)h[(size_t)p0.x * 64 + lane]) << 16);
        float v1 = __uint_as_float(((uint)h[(size_t)p1.x * 64 + lane]) << 16);
        float v2 = __uint_as_float(((uint)h[(size_t)p2.x * 64 + lane]) << 16);
        float v3 = __uint_as_float(((uint)h[(size_t)p3.x * 64 + lane]) << 16);
        acc0 += __int_as_float(p0.y) * v0;
        acc1 += __int_as_float(p1.y) * v1;
        acc2 += __int_as_float(p2.y) * v2;
        acc3 += __int_as_float(p3.y) * v3;
    }
    for (; j < end; j++) {
        int2 p0 = epk[j];
        acc0 += __int_as_float(p0.y) *
                __uint_as_float(((uint)h[(size_t)p0.x * 64 + lane]) << 16);
    }
    float s = (acc0 + acc1) + (acc2 + acc3);
    out[(size_t)wid * 64 + lane] = di * s + di * di * hv + bl;
}

extern "C" void kernel_launch(void* const* d_in, const int* in_sizes, int n_in,
                              void* d_out, int out_size, void* d_ws, size_t ws_size,
                              hipStream_t stream) {
    const float* x  = (const float*)d_in[0];
    const int* ei   = (const int*)d_in[1];
    const float* ew = (const float*)d_in[2];
    const float* W1 = (const float*)d_in[3];
    const float* b1 = (const float*)d_in[4];
    const float* W2 = (const float*)d_in[5];
    const float* b2 = (const float*)d_in[6];
    float* out      = (float*)d_out;

    const int* src = ei;        // edge_index[0]
    const int* dst = ei + EE;   // edge_index[1]

    // workspace layout (4B words; d_ws is 256B-aligned so u64 first is safe):
    u64* dh     = (u64*)d_ws;              // NN u64 = 204800 words
    float* dis  = (float*)(dh + 102400);   // 102400
    int* rowptr = (int*)(dis + 102400);    // 102528 (NN+1 used)
    int* cursor = rowptr + 102528;         // 102400
    int* bsum   = cursor + 102400;         // 512
    int2* epk   = (int2*)(bsum + 512);     // EE int2 = 2*EE words
    ushort* hb  = (ushort*)(epk + EE);     // NN*128 bf16 (reused as h2: NN*64)
    float* a1   = (float*)(hb + (size_t)NN * 128);   // NN*128 fp32

    // --- graph preprocessing (shared by both layers) ---
    k_init<<<NB, 256, 0, stream>>>(dh);
    k_dh<<<EE / 256, 256, 0, stream>>>(dst, ew, dh);
    k_scan_blk<<<NB, 256, 0, stream>>>(dh, dis, rowptr, bsum);
    k_scan_top<<<1, 512, 0, stream>>>(bsum);
    k_scan_add<<<NB, 256, 0, stream>>>(rowptr, bsum, cursor);
    k_scatter<<<EE / 256, 256, 0, stream>>>(src, dst, ew, dis, cursor, epk);

    // --- layer 1 ---
    k_gemm1<<<NN / 32, 256, 0, stream>>>(x, W1, hb);
    k_agg1<<<(NN * 64 + 255) / 256, 256, 0, stream>>>(rowptr, epk, dis, hb, b1, a1);

    // --- layer 2 (h2 reuses hb buffer) ---
    k_gemm2<<<(NN + 63) / 64, 256, 0, stream>>>(a1, W2, hb);
    k_agg2<<<(NN * 64 + 255) / 256, 256, 0, stream>>>(rowptr, epk, dis, hb, b2, out);
}

// Round 9
// 467.674 us; speedup vs baseline: 9.3529x; 1.1507x over previous
//
#include <hip/hip_runtime.h>

#define NN 100000
#define EE 1600000
#define NBKT 391      // ceil(NN/256): buckets of 256 dst nodes
#define NCHK 391      // ceil(EE/4096): edge chunks for count/bin
#define BINCHUNK 4096
#define CAP 5120      // LDS record capacity in k_sort (mean 4092, +16 sigma)

typedef unsigned int uint;
typedef unsigned short ushort;
typedef unsigned long long u64;

__device__ inline ushort f2bf(float f) {          // RNE float->bf16
    uint u = __float_as_uint(f);
    return (ushort)((u + 0x7fffu + ((u >> 16) & 1u)) >> 16);
}
__device__ inline float bf_lo(uint u) { return __uint_as_float(u << 16); }
__device__ inline float bf_hi(uint u) { return __uint_as_float(u & 0xffff0000u); }

// ---------- pass 1: per-bucket edge counts ----------
__global__ __launch_bounds__(256) void k_count(const int* __restrict__ dst,
                                               int* __restrict__ gcount) {
    __shared__ int bh[NBKT];
    int t = threadIdx.x;
    for (int i = t; i < NBKT; i += 256) bh[i] = 0;
    __syncthreads();
    int base = blockIdx.x * BINCHUNK;
    int lim = min(EE - base, BINCHUNK);
    for (int i = t; i < lim; i += 256) atomicAdd(&bh[dst[base + i] >> 8], 1);
    __syncthreads();
    for (int i = t; i < NBKT; i += 256)
        if (bh[i]) atomicAdd(&gcount[i], bh[i]);
}

// ---------- scan bucket counts -> bucket offsets (+cursor init) ----------
__global__ __launch_bounds__(512) void k_bscan(const int* __restrict__ gcount,
                                               int* __restrict__ bofs,
                                               int* __restrict__ gcursor,
                                               int* __restrict__ rowptr) {
    __shared__ int buf[2][512];
    int t = threadIdx.x;
    int v = (t < NBKT) ? gcount[t] : 0;
    int pi = 0;
    buf[0][t] = v;
    __syncthreads();
    for (int off = 1; off < 512; off <<= 1) {
        int po = pi ^ 1;
        int add = (t >= off) ? buf[pi][t - off] : 0;
        buf[po][t] = buf[pi][t] + add;
        __syncthreads();
        pi = po;
    }
    int excl = buf[pi][t] - v;
    if (t < NBKT) { bofs[t] = excl; gcursor[t] = excl; }
    if (t == 0) { bofs[NBKT] = EE; rowptr[NN] = EE; }
}

// ---------- pass 2: bin edges into bucket-major record array ----------
// record u64: [ew_f32 : bits 25..56][src : bits 8..24][dst&255 : bits 0..7]
__global__ __launch_bounds__(256) void k_bin(const int* __restrict__ src,
                                             const int* __restrict__ dst,
                                             const float* __restrict__ ew,
                                             int* __restrict__ gcursor,
                                             u64* __restrict__ recs) {
    __shared__ int bh[NBKT], start[NBKT], lc[NBKT];
    int t = threadIdx.x;
    for (int i = t; i < NBKT; i += 256) { bh[i] = 0; lc[i] = 0; }
    __syncthreads();
    int base = blockIdx.x * BINCHUNK;
    int lim = min(EE - base, BINCHUNK);
    for (int i = t; i < lim; i += 256) atomicAdd(&bh[dst[base + i] >> 8], 1);
    __syncthreads();
    for (int i = t; i < NBKT; i += 256)
        if (bh[i]) start[i] = atomicAdd(&gcursor[i], bh[i]);
    __syncthreads();
    for (int i = t; i < lim; i += 256) {
        int e = base + i;
        int d = dst[e];
        int b = d >> 8;
        int r = atomicAdd(&lc[b], 1);
        recs[start[b] + r] = ((u64)__float_as_uint(ew[e]) << 25) |
                             ((u64)(uint)src[e] << 8) | (u64)(uint)(d & 255);
    }
}

// ---------- pass 3: per-bucket sort by dst + deg/dis/rowptr (in-place epk) ----------
__global__ __launch_bounds__(256) void k_sort(const u64* __restrict__ recs,
                                              const int* __restrict__ bofs,
                                              float* __restrict__ dis,
                                              int* __restrict__ rowptr,
                                              int2* __restrict__ epk) {
    __shared__ u64 rl[CAP];
    __shared__ int hist[256], cur[256];
    __shared__ float degf[256];
    __shared__ int sb[2][256];
    int t = threadIdx.x;
    int b = blockIdx.x;
    int base = bofs[b], cnt = bofs[b + 1] - base;
    hist[t] = 0; cur[t] = 0; degf[t] = 0.f;
    __syncthreads();
    for (int i = t; i < cnt; i += 256) {
        u64 r = recs[base + i];
        if (i < CAP) rl[i] = r;
        int dl = (int)(r & 255);
        atomicAdd(&hist[dl], 1);
        atomicAdd(&degf[dl], __uint_as_float((uint)(r >> 25)));
    }
    __syncthreads();
    // exclusive scan of hist -> per-node local offsets
    int v = hist[t];
    int pi = 0;
    sb[0][t] = v;
    __syncthreads();
    for (int off = 1; off < 256; off <<= 1) {
        int po = pi ^ 1;
        int add = (t >= off) ? sb[pi][t - off] : 0;
        sb[po][t] = sb[pi][t] + add;
        __syncthreads();
        pi = po;
    }
    int lofs = sb[pi][t] - v;
    int node = (b << 8) + t;
    if (node < NN) {
        dis[node] = rsqrtf(1.0f + degf[t]);      // self-loop weight 1
        rowptr[node] = base + lofs;
    }
    hist[t] = lofs;                               // reuse as offset table
    __syncthreads();
    for (int i = t; i < cnt; i += 256) {
        u64 r = (i < CAP) ? rl[i] : recs[base + i];
        int dl = (int)(r & 255);
        int pos = hist[dl] + atomicAdd(&cur[dl], 1);
        epk[base + pos] = make_int2((int)((r >> 8) & 0x1FFFF), (int)(uint)(r >> 25));
    }
}

// ---------- GEMM1: h1[N,128](bf16) = x[N,128] @ W1[128,128] ----------
__global__ __launch_bounds__(256) void k_gemm1(const float* __restrict__ x,
                                               const float* __restrict__ W,
                                               ushort* __restrict__ h) {
    __shared__ float Wl[128 * 128];   // 64 KB
    __shared__ float xt[128 * 32];    // transposed [k][r]
    int t = threadIdx.x;
    int rb = blockIdx.x * 32;

    const float4* W4 = (const float4*)W;
    float4* Wl4 = (float4*)Wl;
#pragma unroll
    for (int i = 0; i < 16; i++) Wl4[t + 256 * i] = W4[t + 256 * i];

#pragma unroll
    for (int i = 0; i < 4; i++) {
        int idx = t + 256 * i;
        int r = idx >> 5;
        int c4 = idx & 31;
        float4 v = ((const float4*)(x + (size_t)(rb + r) * 128))[c4];
        int kc = c4 << 2;
        xt[(kc + 0) * 32 + r] = v.x;
        xt[(kc + 1) * 32 + r] = v.y;
        xt[(kc + 2) * 32 + r] = v.z;
        xt[(kc + 3) * 32 + r] = v.w;
    }
    __syncthreads();

    int tc = t & 31;
    int tr = t >> 5;
    float acc[4][4] = {};
#pragma unroll 4
    for (int k = 0; k < 128; k++) {
        float4 wv = ((const float4*)(Wl + k * 128))[tc];
        float4 xv = ((const float4*)(xt + k * 32))[tr];
        float xs[4] = {xv.x, xv.y, xv.z, xv.w};
        float ws[4] = {wv.x, wv.y, wv.z, wv.w};
#pragma unroll
        for (int r = 0; r < 4; r++)
#pragma unroll
            for (int c = 0; c < 4; c++) acc[r][c] += xs[r] * ws[c];
    }
#pragma unroll
    for (int r = 0; r < 4; r++) {
        int row = rb + tr * 4 + r;
        ushort4 o = {f2bf(acc[r][0]), f2bf(acc[r][1]), f2bf(acc[r][2]), f2bf(acc[r][3])};
        ((ushort4*)(h + (size_t)row * 128))[tc] = o;
    }
}

// ---------- GEMM2: h2[N,64](bf16) = a1[N,128] @ W2[128,64] ----------
__global__ __launch_bounds__(256) void k_gemm2(const float* __restrict__ a,
                                               const float* __restrict__ W,
                                               ushort* __restrict__ h) {
    __shared__ float Wl[128 * 64];
    __shared__ float at[128 * 64];
    int t = threadIdx.x;
    int rb = blockIdx.x * 64;

    const float4* W4 = (const float4*)W;
    float4* Wl4 = (float4*)Wl;
#pragma unroll
    for (int i = 0; i < 8; i++) Wl4[t + 256 * i] = W4[t + 256 * i];

#pragma unroll
    for (int i = 0; i < 8; i++) {
        int idx = t + 256 * i;
        int r = idx >> 5;
        int c4 = idx & 31;
        int row = rb + r;
        if (row >= NN) row = NN - 1;
        float4 v = ((const float4*)(a + (size_t)row * 128))[c4];
        int kc = c4 << 2;
        at[(kc + 0) * 64 + r] = v.x;
        at[(kc + 1) * 64 + r] = v.y;
        at[(kc + 2) * 64 + r] = v.z;
        at[(kc + 3) * 64 + r] = v.w;
    }
    __syncthreads();

    int tc = t & 15;
    int tr = t >> 4;
    float acc[4][4] = {};
#pragma unroll 4
    for (int k = 0; k < 128; k++) {
        float4 wv = ((const float4*)(Wl + k * 64))[tc];
        float4 av = ((const float4*)(at + k * 64))[tr];
        float as[4] = {av.x, av.y, av.z, av.w};
        float ws[4] = {wv.x, wv.y, wv.z, wv.w};
#pragma unroll
        for (int r = 0; r < 4; r++)
#pragma unroll
            for (int c = 0; c < 4; c++) acc[r][c] += as[r] * ws[c];
    }
#pragma unroll
    for (int r = 0; r < 4; r++) {
        int row = rb + tr * 4 + r;
        if (row < NN) {
            ushort4 o = {f2bf(acc[r][0]), f2bf(acc[r][1]), f2bf(acc[r][2]), f2bf(acc[r][3])};
            ((ushort4*)(h + (size_t)row * 64))[tc] = o;
        }
    }
}

// ---------- layer-1 CSR aggregation: one wave per dst node, 4-way MLP ----------
// a1[d] = relu( dis[d] * sum_e dis[s]*ew*h1[s] + dis[d]^2 * h1[d] + b1 )
__global__ __launch_bounds__(256) void k_agg1(const int* __restrict__ rowptr,
                                              const int2* __restrict__ epk,
                                              const float* __restrict__ dis,
                                              const ushort* __restrict__ h,
                                              const float* __restrict__ b,
                                              float* __restrict__ a) {
    int wid = (blockIdx.x * blockDim.x + threadIdx.x) >> 6;   // node id
    int lane = threadIdx.x & 63;
    if (wid >= NN) return;
    int beg = rowptr[wid], end = rowptr[wid + 1];
    const uint* hp = (const uint*)h;             // 64 uints (=128 bf16) per row
    uint us = hp[(size_t)wid * 64 + lane];
    float di = dis[wid];
    float2 bv = ((const float2*)b)[lane];

    float2 acc0 = {0.f, 0.f}, acc1 = {0.f, 0.f};
    float2 acc2 = {0.f, 0.f}, acc3 = {0.f, 0.f};
    int j = beg;
    for (; j + 3 < end; j += 4) {
        int2 p0 = epk[j];
        int2 p1 = epk[j + 1];
        int2 p2 = epk[j + 2];
        int2 p3 = epk[j + 3];
        uint u0 = hp[(size_t)p0.x * 64 + lane];
        uint u1 = hp[(size_t)p1.x * 64 + lane];
        uint u2 = hp[(size_t)p2.x * 64 + lane];
        uint u3 = hp[(size_t)p3.x * 64 + lane];
        float w0 = dis[p0.x] * __int_as_float(p0.y);
        float w1 = dis[p1.x] * __int_as_float(p1.y);
        float w2 = dis[p2.x] * __int_as_float(p2.y);
        float w3 = dis[p3.x] * __int_as_float(p3.y);
        acc0.x += w0 * bf_lo(u0); acc0.y += w0 * bf_hi(u0);
        acc1.x += w1 * bf_lo(u1); acc1.y += w1 * bf_hi(u1);
        acc2.x += w2 * bf_lo(u2); acc2.y += w2 * bf_hi(u2);
        acc3.x += w3 * bf_lo(u3); acc3.y += w3 * bf_hi(u3);
    }
    for (; j < end; j++) {
        int2 p0 = epk[j];
        float w0 = dis[p0.x] * __int_as_float(p0.y);
        uint u0 = hp[(size_t)p0.x * 64 + lane];
        acc0.x += w0 * bf_lo(u0); acc0.y += w0 * bf_hi(u0);
    }
    float sx = (acc0.x + acc1.x) + (acc2.x + acc3.x);
    float sy = (acc0.y + acc1.y) + (acc2.y + acc3.y);
    float ox = di * sx + di * di * bf_lo(us) + bv.x;
    float oy = di * sy + di * di * bf_hi(us) + bv.y;
    float2 o = {fmaxf(ox, 0.f), fmaxf(oy, 0.f)};
    ((float2*)a)[(size_t)wid * 64 + lane] = o;
}

// ---------- layer-2 CSR aggregation: one wave per dst node, 4-way MLP ----------
__global__ __launch_bounds__(256) void k_agg2(const int* __restrict__ rowptr,
                                              const int2* __restrict__ epk,
                                              const float* __restrict__ dis,
                                              const ushort* __restrict__ h,
                                              const float* __restrict__ b,
                                              float* __restrict__ out) {
    int wid = (blockIdx.x * blockDim.x + threadIdx.x) >> 6;
    int lane = threadIdx.x & 63;
    if (wid >= NN) return;
    int beg = rowptr[wid], end = rowptr[wid + 1];
    float hv = __uint_as_float(((uint)h[(size_t)wid * 64 + lane]) << 16);
    float di = dis[wid];
    float bl = b[lane];

    float acc0 = 0.f, acc1 = 0.f, acc2 = 0.f, acc3 = 0.f;
    int j = beg;
    for (; j + 3 < end; j += 4) {
        int2 p0 = epk[j];
        int2 p1 = epk[j + 1];
        int2 p2 = epk[j + 2];
        int2 p3 = epk[j + 3];
        float v0 = __uint_as_float(((uint)h[(size_t)p0.x * 64 + lane]) << 16);
        float v1 = __uint_as_float(((uint)h[(size_t)p1.x * 64 + lane]) << 16);
        float v2 = __uint_as_float(((uint)h[(size_t)p2.x * 64 + lane]) << 16);
        float v3 = __uint_as_float(((uint)h[(size_t)p3.x * 64 + lane]) << 16);
        acc0 += dis[p0.x] * __int_as_float(p0.y) * v0;
        acc1 += dis[p1.x] * __int_as_float(p1.y) * v1;
        acc2 += dis[p2.x] * __int_as_float(p2.y) * v2;
        acc3 += dis[p3.x] * __int_as_float(p3.y) * v3;
    }
    for (; j < end; j++) {
        int2 p0 = epk[j];
        acc0 += dis[p0.x] * __int_as_float(p0.y) *
                __uint_as_float(((uint)h[(size_t)p0.x * 64 + lane]) << 16);
    }
    float s = (acc0 + acc1) + (acc2 + acc3);
    out[(size_t)wid * 64 + lane] = di * s + di * di * hv + bl;
}

extern "C" void kernel_launch(void* const* d_in, const int* in_sizes, int n_in,
                              void* d_out, int out_size, void* d_ws, size_t ws_size,
                              hipStream_t stream) {
    const float* x  = (const float*)d_in[0];
    const int* ei   = (const int*)d_in[1];
    const float* ew = (const float*)d_in[2];
    const float* W1 = (const float*)d_in[3];
    const float* b1 = (const float*)d_in[4];
    const float* W2 = (const float*)d_in[5];
    const float* b2 = (const float*)d_in[6];
    float* out      = (float*)d_out;

    const int* src = ei;        // edge_index[0]
    const int* dst = ei + EE;   // edge_index[1]

    // workspace layout (4B words):
    int* gcount  = (int*)d_ws;             // 512
    int* bofs    = gcount + 512;           // 512 (NBKT+1 used)
    int* gcursor = bofs + 512;             // 512
    float* dis   = (float*)(gcursor + 512);// 100000
    int* rowptr  = (int*)(dis + 100000);   // 100001 -> pad to 100002 (even)
    u64* recs    = (u64*)(rowptr + 100002);// EE u64 (word idx 101538+100002... 8B aligned)
    int2* epk    = (int2*)recs;            // ALIAS: sorted in place by k_sort
    ushort* hb   = (ushort*)(recs + EE);   // NN*128 bf16 (reused as h2: NN*64)
    float* a1    = (float*)(hb + (size_t)NN * 128);   // NN*128 fp32

    // --- graph preprocessing (shared by both layers) ---
    hipMemsetAsync(gcount, 0, 512 * sizeof(int), stream);
    k_count<<<NCHK, 256, 0, stream>>>(dst, gcount);
    k_bscan<<<1, 512, 0, stream>>>(gcount, bofs, gcursor, rowptr);
    k_bin<<<NCHK, 256, 0, stream>>>(src, dst, ew, gcursor, recs);
    k_sort<<<NBKT, 256, 0, stream>>>(recs, bofs, dis, rowptr, epk);

    // --- layer 1 ---
    k_gemm1<<<NN / 32, 256, 0, stream>>>(x, W1, hb);
    k_agg1<<<(NN * 64 + 255) / 256, 256, 0, stream>>>(rowptr, epk, dis, hb, b1, a1);

    // --- layer 2 (h2 reuses hb buffer) ---
    k_gemm2<<<(NN + 63) / 64, 256, 0, stream>>>(a1, W2, hb);
    k_agg2<<<(NN * 64 + 255) / 256, 256, 0, stream>>>(rowptr, epk, dis, hb, b2, out);
}

// Round 12
// 458.402 us; speedup vs baseline: 9.5421x; 1.0202x over previous
//
#include <hip/hip_runtime.h>

#define NN 100000
#define EE 1600000
#define NBKT 391      // ceil(NN/256): buckets of 256 dst nodes
#define NCHK 391      // ceil(EE/4096): edge chunks for count/bin
#define BINCHUNK 4096
#define CAP 5120      // LDS record capacity in k_sort (mean 4092, +16 sigma)

typedef unsigned int uint;
typedef unsigned short ushort;
typedef unsigned long long u64;

__device__ inline ushort f2bf(float f) {          // RNE float->bf16
    uint u = __float_as_uint(f);
    return (ushort)((u + 0x7fffu + ((u >> 16) & 1u)) >> 16);
}
__device__ inline float bf_lo(uint u) { return __uint_as_float(u << 16); }
__device__ inline float bf_hi(uint u) { return __uint_as_float(u & 0xffff0000u); }

// ---------- pass 1: per-bucket edge counts ----------
__global__ __launch_bounds__(256) void k_count(const int* __restrict__ dst,
                                               int* __restrict__ gcount) {
    __shared__ int bh[NBKT];
    int t = threadIdx.x;
    for (int i = t; i < NBKT; i += 256) bh[i] = 0;
    __syncthreads();
    int base = blockIdx.x * BINCHUNK;
    int lim = min(EE - base, BINCHUNK);
    for (int i = t; i < lim; i += 256) atomicAdd(&bh[dst[base + i] >> 8], 1);
    __syncthreads();
    for (int i = t; i < NBKT; i += 256)
        if (bh[i]) atomicAdd(&gcount[i], bh[i]);
}

// ---------- scan bucket counts -> bucket offsets (+cursor init) ----------
__global__ __launch_bounds__(512) void k_bscan(const int* __restrict__ gcount,
                                               int* __restrict__ bofs,
                                               int* __restrict__ gcursor,
                                               int* __restrict__ rowptr) {
    __shared__ int buf[2][512];
    int t = threadIdx.x;
    int v = (t < NBKT) ? gcount[t] : 0;
    int pi = 0;
    buf[0][t] = v;
    __syncthreads();
    for (int off = 1; off < 512; off <<= 1) {
        int po = pi ^ 1;
        int add = (t >= off) ? buf[pi][t - off] : 0;
        buf[po][t] = buf[pi][t] + add;
        __syncthreads();
        pi = po;
    }
    int excl = buf[pi][t] - v;
    if (t < NBKT) { bofs[t] = excl; gcursor[t] = excl; }
    if (t == 0) { bofs[NBKT] = EE; rowptr[NN] = EE; }
}

// ---------- pass 2: bin edges into bucket-major record array ----------
// record u64: [ew_f32 : bits 25..56][src : bits 8..24][dst&255 : bits 0..7]
__global__ __launch_bounds__(256) void k_bin(const int* __restrict__ src,
                                             const int* __restrict__ dst,
                                             const float* __restrict__ ew,
                                             int* __restrict__ gcursor,
                                             u64* __restrict__ recs) {
    __shared__ int bh[NBKT], start[NBKT], lc[NBKT];
    int t = threadIdx.x;
    for (int i = t; i < NBKT; i += 256) { bh[i] = 0; lc[i] = 0; }
    __syncthreads();
    int base = blockIdx.x * BINCHUNK;
    int lim = min(EE - base, BINCHUNK);
    for (int i = t; i < lim; i += 256) atomicAdd(&bh[dst[base + i] >> 8], 1);
    __syncthreads();
    for (int i = t; i < NBKT; i += 256)
        if (bh[i]) start[i] = atomicAdd(&gcursor[i], bh[i]);
    __syncthreads();
    for (int i = t; i < lim; i += 256) {
        int e = base + i;
        int d = dst[e];
        int b = d >> 8;
        int r = atomicAdd(&lc[b], 1);
        recs[start[b] + r] = ((u64)__float_as_uint(ew[e]) << 25) |
                             ((u64)(uint)src[e] << 8) | (u64)(uint)(d & 255);
    }
}

// ---------- pass 3: per-bucket sort by dst + deg/dis/rowptr (in-place epk) ----------
__global__ __launch_bounds__(256) void k_sort(const u64* __restrict__ recs,
                                              const int* __restrict__ bofs,
                                              float* __restrict__ dis,
                                              int* __restrict__ rowptr,
                                              int2* __restrict__ epk) {
    __shared__ u64 rl[CAP];
    __shared__ int hist[256], cur[256];
    __shared__ float degf[256];
    __shared__ int sb[2][256];
    int t = threadIdx.x;
    int b = blockIdx.x;
    int base = bofs[b], cnt = bofs[b + 1] - base;
    hist[t] = 0; cur[t] = 0; degf[t] = 0.f;
    __syncthreads();
    for (int i = t; i < cnt; i += 256) {
        u64 r = recs[base + i];
        if (i < CAP) rl[i] = r;
        int dl = (int)(r & 255);
        atomicAdd(&hist[dl], 1);
        atomicAdd(&degf[dl], __uint_as_float((uint)(r >> 25)));
    }
    __syncthreads();
    // exclusive scan of hist -> per-node local offsets
    int v = hist[t];
    int pi = 0;
    sb[0][t] = v;
    __syncthreads();
    for (int off = 1; off < 256; off <<= 1) {
        int po = pi ^ 1;
        int add = (t >= off) ? sb[pi][t - off] : 0;
        sb[po][t] = sb[pi][t] + add;
        __syncthreads();
        pi = po;
    }
    int lofs = sb[pi][t] - v;
    int node = (b << 8) + t;
    if (node < NN) {
        dis[node] = rsqrtf(1.0f + degf[t]);      // self-loop weight 1
        rowptr[node] = base + lofs;
    }
    hist[t] = lofs;                               // reuse as offset table
    __syncthreads();
    for (int i = t; i < cnt; i += 256) {
        u64 r = (i < CAP) ? rl[i] : recs[base + i];
        int dl = (int)(r & 255);
        int pos = hist[dl] + atomicAdd(&cur[dl], 1);
        epk[base + pos] = make_int2((int)((r >> 8) & 0x1FFFF), (int)(uint)(r >> 25));
    }
}

// ---------- pass 4: fold dis[src] into stored weight (L2-friendly) ----------
__global__ __launch_bounds__(256) void k_wmul(int2* __restrict__ epk,
                                              const float* __restrict__ dis) {
    int e = blockIdx.x * blockDim.x + threadIdx.x;
    if (e >= EE) return;
    int2 p = epk[e];
    float w = dis[p.x] * __int_as_float(p.y);
    epk[e] = make_int2(p.x, __float_as_int(w));
}

// ---------- GEMM1: h1[N,128](bf16) = x[N,128] @ W1[128,128] ----------
__global__ __launch_bounds__(256) void k_gemm1(const float* __restrict__ x,
                                               const float* __restrict__ W,
                                               ushort* __restrict__ h) {
    __shared__ float Wl[128 * 128];   // 64 KB
    __shared__ float xt[128 * 32];    // transposed [k][r]
    int t = threadIdx.x;
    int rb = blockIdx.x * 32;

    const float4* W4 = (const float4*)W;
    float4* Wl4 = (float4*)Wl;
#pragma unroll
    for (int i = 0; i < 16; i++) Wl4[t + 256 * i] = W4[t + 256 * i];

#pragma unroll
    for (int i = 0; i < 4; i++) {
        int idx = t + 256 * i;
        int r = idx >> 5;
        int c4 = idx & 31;
        float4 v = ((const float4*)(x + (size_t)(rb + r) * 128))[c4];
        int kc = c4 << 2;
        xt[(kc + 0) * 32 + r] = v.x;
        xt[(kc + 1) * 32 + r] = v.y;
        xt[(kc + 2) * 32 + r] = v.z;
        xt[(kc + 3) * 32 + r] = v.w;
    }
    __syncthreads();

    int tc = t & 31;
    int tr = t >> 5;
    float acc[4][4] = {};
#pragma unroll 4
    for (int k = 0; k < 128; k++) {
        float4 wv = ((const float4*)(Wl + k * 128))[tc];
        float4 xv = ((const float4*)(xt + k * 32))[tr];
        float xs[4] = {xv.x, xv.y, xv.z, xv.w};
        float ws[4] = {wv.x, wv.y, wv.z, wv.w};
#pragma unroll
        for (int r = 0; r < 4; r++)
#pragma unroll
            for (int c = 0; c < 4; c++) acc[r][c] += xs[r] * ws[c];
    }
#pragma unroll
    for (int r = 0; r < 4; r++) {
        int row = rb + tr * 4 + r;
        ushort4 o = {f2bf(acc[r][0]), f2bf(acc[r][1]), f2bf(acc[r][2]), f2bf(acc[r][3])};
        ((ushort4*)(h + (size_t)row * 128))[tc] = o;
    }
}

// ---------- GEMM2: h2[N,64](bf16) = a1[N,128] @ W2[128,64] ----------
__global__ __launch_bounds__(256) void k_gemm2(const float* __restrict__ a,
                                               const float* __restrict__ W,
                                               ushort* __restrict__ h) {
    __shared__ float Wl[128 * 64];
    __shared__ float at[128 * 64];
    int t = threadIdx.x;
    int rb = blockIdx.x * 64;

    const float4* W4 = (const float4*)W;
    float4* Wl4 = (float4*)Wl;
#pragma unroll
    for (int i = 0; i < 8; i++) Wl4[t + 256 * i] = W4[t + 256 * i];

#pragma unroll
    for (int i = 0; i < 8; i++) {
        int idx = t + 256 * i;
        int r = idx >> 5;
        int c4 = idx & 31;
        int row = rb + r;
        if (row >= NN) row = NN - 1;
        float4 v = ((const float4*)(a + (size_t)row * 128))[c4];
        int kc = c4 << 2;
        at[(kc + 0) * 64 + r] = v.x;
        at[(kc + 1) * 64 + r] = v.y;
        at[(kc + 2) * 64 + r] = v.z;
        at[(kc + 3) * 64 + r] = v.w;
    }
    __syncthreads();

    int tc = t & 15;
    int tr = t >> 4;
    float acc[4][4] = {};
#pragma unroll 4
    for (int k = 0; k < 128; k++) {
        float4 wv = ((const float4*)(Wl + k * 64))[tc];
        float4 av = ((const float4*)(at + k * 64))[tr];
        float as[4] = {av.x, av.y, av.z, av.w};
        float ws[4] = {wv.x, wv.y, wv.z, wv.w};
#pragma unroll
        for (int r = 0; r < 4; r++)
#pragma unroll
            for (int c = 0; c < 4; c++) acc[r][c] += as[r] * ws[c];
    }
#pragma unroll
    for (int r = 0; r < 4; r++) {
        int row = rb + tr * 4 + r;
        if (row < NN) {
            ushort4 o = {f2bf(acc[r][0]), f2bf(acc[r][1]), f2bf(acc[r][2]), f2bf(acc[r][3])};
            ((ushort4*)(h + (size_t)row * 64))[tc] = o;
        }
    }
}

// ---------- layer-1 CSR aggregation: one wave per dst node, 8-way MLP ----------
// a1[d] = relu( dis[d] * sum_e w[e]*h1[src[e]] + dis[d]^2 * h1[d] + b1 )
__global__ __launch_bounds__(256) void k_agg1(const int* __restrict__ rowptr,
                                              const int2* __restrict__ epk,
                                              const float* __restrict__ dis,
                                              const ushort* __restrict__ h,
                                              const float* __restrict__ b,
                                              float* __restrict__ a) {
    int wid = (blockIdx.x * blockDim.x + threadIdx.x) >> 6;   // node id
    int lane = threadIdx.x & 63;
    if (wid >= NN) return;
    int beg = rowptr[wid], end = rowptr[wid + 1];
    const uint* hp = (const uint*)h;             // 64 uints (=128 bf16) per row
    uint us = hp[(size_t)wid * 64 + lane];
    float di = dis[wid];
    float2 bv = ((const float2*)b)[lane];

    float2 acc0 = {0.f, 0.f}, acc1 = {0.f, 0.f};
    float2 acc2 = {0.f, 0.f}, acc3 = {0.f, 0.f};
    int j = beg;
    for (; j + 7 < end; j += 8) {
        int2 p0 = epk[j];
        int2 p1 = epk[j + 1];
        int2 p2 = epk[j + 2];
        int2 p3 = epk[j + 3];
        int2 p4 = epk[j + 4];
        int2 p5 = epk[j + 5];
        int2 p6 = epk[j + 6];
        int2 p7 = epk[j + 7];
        uint u0 = hp[(size_t)p0.x * 64 + lane];
        uint u1 = hp[(size_t)p1.x * 64 + lane];
        uint u2 = hp[(size_t)p2.x * 64 + lane];
        uint u3 = hp[(size_t)p3.x * 64 + lane];
        uint u4 = hp[(size_t)p4.x * 64 + lane];
        uint u5 = hp[(size_t)p5.x * 64 + lane];
        uint u6 = hp[(size_t)p6.x * 64 + lane];
        uint u7 = hp[(size_t)p7.x * 64 + lane];
        float w0 = __int_as_float(p0.y);
        float w1 = __int_as_float(p1.y);
        float w2 = __int_as_float(p2.y);
        float w3 = __int_as_float(p3.y);
        float w4 = __int_as_float(p4.y);
        float w5 = __int_as_float(p5.y);
        float w6 = __int_as_float(p6.y);
        float w7 = __int_as_float(p7.y);
        acc0.x += w0 * bf_lo(u0); acc0.y += w0 * bf_hi(u0);
        acc1.x += w1 * bf_lo(u1); acc1.y += w1 * bf_hi(u1);
        acc2.x += w2 * bf_lo(u2); acc2.y += w2 * bf_hi(u2);
        acc3.x += w3 * bf_lo(u3); acc3.y += w3 * bf_hi(u3);
        acc0.x += w4 * bf_lo(u4); acc0.y += w4 * bf_hi(u4);
        acc1.x += w5 * bf_lo(u5); acc1.y += w5 * bf_hi(u5);
        acc2.x += w6 * bf_lo(u6); acc2.y += w6 * bf_hi(u6);
        acc3.x += w7 * bf_lo(u7); acc3.y += w7 * bf_hi(u7);
    }
    for (; j + 1 < end; j += 2) {
        int2 p0 = epk[j];
        int2 p1 = epk[j + 1];
        uint u0 = hp[(size_t)p0.x * 64 + lane];
        uint u1 = hp[(size_t)p1.x * 64 + lane];
        float w0 = __int_as_float(p0.y);
        float w1 = __int_as_float(p1.y);
        acc0.x += w0 * bf_lo(u0); acc0.y += w0 * bf_hi(u0);
        acc1.x += w1 * bf_lo(u1); acc1.y += w1 * bf_hi(u1);
    }
    if (j < end) {
        int2 p0 = epk[j];
        float w0 = __int_as_float(p0.y);
        uint u0 = hp[(size_t)p0.x * 64 + lane];
        acc0.x += w0 * bf_lo(u0); acc0.y += w0 * bf_hi(u0);
    }
    float sx = (acc0.x + acc1.x) + (acc2.x + acc3.x);
    float sy = (acc0.y + acc1.y) + (acc2.y + acc3.y);
    float ox = di * sx + di * di * bf_lo(us) + bv.x;
    float oy = di * sy + di * di * bf_hi(us) + bv.y;
    float2 o = {fmaxf(ox, 0.f), fmaxf(oy, 0.f)};
    ((float2*)a)[(size_t)wid * 64 + lane] = o;
}

// ---------- layer-2 CSR aggregation: one wave per dst node, 8-way MLP ----------
__global__ __launch_bounds__(256) void k_agg2(const int* __restrict__ rowptr,
                                              const int2* __restrict__ epk,
                                              const float* __restrict__ dis,
                                              const ushort* __restrict__ h,
                                              const float* __restrict__ b,
                                              float* __restrict__ out) {
    int wid = (blockIdx.x * blockDim.x + threadIdx.x) >> 6;
    int lane = threadIdx.x & 63;
    if (wid >= NN) return;
    int beg = rowptr[wid], end = rowptr[wid + 1];
    float hv = __uint_as_float(((uint)h[(size_t)wid * 64 + lane]) << 16);
    float di = dis[wid];
    float bl = b[lane];

    float acc0 = 0.f, acc1 = 0.f, acc2 = 0.f, acc3 = 0.f;
    int j = beg;
    for (; j + 7 < end; j += 8) {
        int2 p0 = epk[j];
        int2 p1 = epk[j + 1];
        int2 p2 = epk[j + 2];
        int2 p3 = epk[j + 3];
        int2 p4 = epk[j + 4];
        int2 p5 = epk[j + 5];
        int2 p6 = epk[j + 6];
        int2 p7 = epk[j + 7];
        float v0 = __uint_as_float(((uint)h[(size_t)p0.x * 64 + lane]) << 16);
        float v1 = __uint_as_float(((uint)h[(size_t)p1.x * 64 + lane]) << 16);
        float v2 = __uint_as_float(((uint)h[(size_t)p2.x * 64 + lane]) << 16);
        float v3 = __uint_as_float(((uint)h[(size_t)p3.x * 64 + lane]) << 16);
        float v4 = __uint_as_float(((uint)h[(size_t)p4.x * 64 + lane]) << 16);
        float v5 = __uint_as_float(((uint)h[(size_t)p5.x * 64 + lane]) << 16);
        float v6 = __uint_as_float(((uint)h[(size_t)p6.x * 64 + lane]) << 16);
        float v7 = __uint_as_float(((uint)h[(size_t)p7.x * 64 + lane]) << 16);
        acc0 += __int_as_float(p0.y) * v0;
        acc1 += __int_as_float(p1.y) * v1;
        acc2 += __int_as_float(p2.y) * v2;
        acc3 += __int_as_float(p3.y) * v3;
        acc0 += __int_as_float(p4.y) * v4;
        acc1 += __int_as_float(p5.y) * v5;
        acc2 += __int_as_float(p6.y) * v6;
        acc3 += __int_as_float(p7.y) * v7;
    }
    for (; j + 1 < end; j += 2) {
        int2 p0 = epk[j];
        int2 p1 = epk[j + 1];
        float v0 = __uint_as_float(((uint)h[(size_t)p0.x * 64 + lane]) << 16);
        float v1 = __uint_as_float(((uint)h[(size_t)p1.x * 64 + lane]) << 16);
        acc0 += __int_as_float(p0.y) * v0;
        acc1 += __int_as_float(p1.y) * v1;
    }
    if (j < end) {
        int2 p0 = epk[j];
        acc0 += __int_as_float(p0.y) *
                __uint_as_float(((uint)h[(size_t)p0.x * 64 + lane]) << 16);
    }
    float s = (acc0 + acc1) + (acc2 + acc3);
    out[(size_t)wid * 64 + lane] = di * s + di * di * hv + bl;
}

extern "C" void kernel_launch(void* const* d_in, const int* in_sizes, int n_in,
                              void* d_out, int out_size, void* d_ws, size_t ws_size,
                              hipStream_t stream) {
    const float* x  = (const float*)d_in[0];
    const int* ei   = (const int*)d_in[1];
    const float* ew = (const float*)d_in[2];
    const float* W1 = (const float*)d_in[3];
    const float* b1 = (const float*)d_in[4];
    const float* W2 = (const float*)d_in[5];
    const float* b2 = (const float*)d_in[6];
    float* out      = (float*)d_out;

    const int* src = ei;        // edge_index[0]
    const int* dst = ei + EE;   // edge_index[1]

    // workspace layout (4B words):
    int* gcount  = (int*)d_ws;             // 512
    int* bofs    = gcount + 512;           // 512 (NBKT+1 used)
    int* gcursor = bofs + 512;             // 512
    float* dis   = (float*)(gcursor + 512);// 100000
    int* rowptr  = (int*)(dis + 100000);   // 100001 -> pad to 100002 (even)
    u64* recs    = (u64*)(rowptr + 100002);// EE u64 (8B aligned)
    int2* epk    = (int2*)recs;            // ALIAS: sorted in place by k_sort
    ushort* hb   = (ushort*)(recs + EE);   // NN*128 bf16 (reused as h2: NN*64)
    float* a1    = (float*)(hb + (size_t)NN * 128);   // NN*128 fp32

    // --- graph preprocessing (shared by both layers) ---
    hipMemsetAsync(gcount, 0, 512 * sizeof(int), stream);
    k_count<<<NCHK, 256, 0, stream>>>(dst, gcount);
    k_bscan<<<1, 512, 0, stream>>>(gcount, bofs, gcursor, rowptr);
    k_bin<<<NCHK, 256, 0, stream>>>(src, dst, ew, gcursor, recs);
    k_sort<<<NBKT, 256, 0, stream>>>(recs, bofs, dis, rowptr, epk);
    k_wmul<<<(EE + 255) / 256, 256, 0, stream>>>(epk, dis);

    // --- layer 1 ---
    k_gemm1<<<NN / 32, 256, 0, stream>>>(x, W1, hb);
    k_agg1<<<(NN * 64 + 255) / 256, 256, 0, stream>>>(rowptr, epk, dis, hb, b1, a1);

    // --- layer 2 (h2 reuses hb buffer) ---
    k_gemm2<<<(NN + 63) / 64, 256, 0, stream>>>(a1, W2, hb);
    k_agg2<<<(NN * 64 + 255) / 256, 256, 0, stream>>>(rowptr, epk, dis, hb, b2, out);
}